// Round 6
// baseline (2895.611 us; speedup 1.0000x reference)
//
#include <hip/hip_runtime.h>
#include <hip/hip_bf16.h>
#include <math.h>

typedef unsigned int u32;
typedef unsigned long long u64;
typedef unsigned short u16;
typedef __attribute__((ext_vector_type(8))) short short8;
typedef __attribute__((ext_vector_type(4))) float f32x4;
typedef __attribute__((ext_vector_type(4))) int v4i;

#define PI_F 3.14159265358979f
#define B_   512
#define T_   256
#define DIN  128
#define H_   256
#define G4   1024
#define F_   64
#define E_   320
#define DM   384
#define NL1  512
#define NACT 8
#define KMLP 394

// Raw buffer intrinsics with explicit cache policy. aux=17 = SC0|SC1:
// bypass L1+L2, read/write at the device coherence point (MALL). The ONLY
// scope proven (R0-R5) for cross-block store->load visibility.
__device__ v4i llvm_amdgcn_raw_buffer_load_v4i32(v4i rsrc, int voffset,
                                                 int soffset, int aux)
    __asm("llvm.amdgcn.raw.buffer.load.v4i32");
__device__ void llvm_amdgcn_raw_buffer_store_i32(int vdata, v4i rsrc,
                                                 int voffset, int soffset,
                                                 int aux)
    __asm("llvm.amdgcn.raw.buffer.store.i32");

__device__ __forceinline__ v4i make_srd(const void* p) {
  v4i r;
  r.x = (int)(u32)(u64)p;
  r.y = (int)(u32)((u64)p >> 32);   // base hi, stride=0
  r.z = (int)0xFFFFFFFFu;           // num_records: bounds check disabled
  r.w = 0x00020000;                 // raw untyped dword access
  return r;
}

__device__ __forceinline__ float b2f(u16 h) {
  union { u32 u; float f; } v; v.u = ((u32)h) << 16; return v.f;
}
__device__ __forceinline__ u16 f2b(float f) {
  union { float f; u32 u; } v; v.f = f;
  u32 r = (v.u + 0x7FFFu + ((v.u >> 16) & 1u)) >> 16;
  return (u16)r;
}
__device__ __forceinline__ float sigf(float x) { return 1.0f / (1.0f + __expf(-x)); }
__device__ __forceinline__ float tanhfast(float x) { return 2.0f / (1.0f + __expf(-2.0f * x)) - 1.0f; }
__device__ __forceinline__ float2 cmul(float2 a, float2 b) {
  return make_float2(a.x * b.x - a.y * b.y, a.x * b.y + a.y * b.x);
}
__device__ __forceinline__ float2 cadd(float2 a, float2 b) {
  return make_float2(a.x + b.x, a.y + b.y);
}

// Sentinel: bf16 pair 0xFF80 = -inf. h = sig(o)*tanh(c) in (-1,1) can never
// produce it; dword stores are single-copy atomic -> each dword is SENT or
// final data, never torn. Proven correct in R3.
#define SENT 0xFF80FF80u

// ---------------------------------------------------------------------------
// prep1: x transpose+bf16, Wg=[W_ih|W_hh] bf16, zero hs[0], W1t, bb, cnt, uw,
// bkp, bvp, sentinel-fill hs[1..256]
// ---------------------------------------------------------------------------
__global__ void k_prep1(const float* __restrict__ lstm_s,
                        const float* __restrict__ W_ih,
                        const float* __restrict__ W_hh,
                        const float* __restrict__ b_ih,
                        const float* __restrict__ b_hh,
                        const float* __restrict__ ipw,
                        const float* __restrict__ ipb,
                        const float* __restrict__ projb,
                        const float* __restrict__ qw,
                        const float* __restrict__ W1,
                        u16* __restrict__ xbf,
                        u16* __restrict__ hs,
                        u16* __restrict__ Wg,
                        float* __restrict__ bb,
                        float* __restrict__ W1t,
                        float* __restrict__ uw,
                        float* __restrict__ bkp,
                        float* __restrict__ bvp,
                        u32* __restrict__ cnt) {
  const int bid = blockIdx.x;
  const int tid = threadIdx.x;
  if (bid < 8192) {                       // lstm_s (B,T,128) -> xbf (T,B,128) bf16
    u32 u = (u32)bid * 256u + tid;        // < 2097152 uint4 units
    u32 c8 = u & 15u, b = (u >> 4) & 511u, t = u >> 13;
    const float* src = lstm_s + ((size_t)b * T_ + t) * DIN + c8 * 8;
    union { u16 h[8]; uint4 v; } tmp;
#pragma unroll
    for (int i = 0; i < 8; ++i) tmp.h[i] = f2b(src[i]);
    *(uint4*)(xbf + ((size_t)t * B_ + b) * DIN + c8 * 8) = tmp.v;
  } else if (bid < 8384) {                // Wg (1024 x 384) bf16
    u32 u = (u32)(bid - 8192) * 256u + tid;  // < 49152
    u32 c8 = u % 48u, r = u / 48u;
    const float* src = (c8 < 16) ? (W_ih + (size_t)r * DIN + c8 * 8)
                                 : (W_hh + (size_t)r * H_ + (c8 - 16) * 8);
    union { u16 h[8]; uint4 v; } tmp;
#pragma unroll
    for (int i = 0; i < 8; ++i) tmp.h[i] = f2b(src[i]);
    *(uint4*)(Wg + (size_t)r * 384 + c8 * 8) = tmp.v;
  } else if (bid < 8448) {                // zero hs[0] (REAL zeros, not sentinel)
    u32 u = (u32)(bid - 8384) * 256u + tid;  // < 16384
    ((uint4*)hs)[u] = make_uint4(0, 0, 0, 0);
  } else if (bid < 9236) {                // W1t[k][n] = W1[n][k]
    u32 u = (u32)(bid - 8448) * 256u + tid;  // < 201728
    u32 k = u / 512u, nn = u % 512u;
    W1t[u] = W1[(size_t)nn * KMLP + k];
  } else if (bid == 9236) {               // bb, cnt, uw
    for (int i = tid; i < 1024; i += 256) bb[i] = b_ih[i] + b_hh[i];
    for (int i = tid; i < 1024; i += 256) cnt[i] = 0u;
    if (tid < 40) {
      float w0 = qw[tid * 3 + 0], w1 = qw[tid * 3 + 1], w2 = qw[tid * 3 + 2];
      float c0 = cosf(0.5f * w0), s0 = sinf(0.5f * w0);
      float c1 = cosf(0.5f * w1), s1 = sinf(0.5f * w1);
      float c2 = cosf(0.5f * w2), s2 = sinf(0.5f * w2);
      float2 e0m = make_float2(c0, -s0), e0p = make_float2(c0, s0);
      float2 e2m = make_float2(c2, -s2), e2p = make_float2(c2, s2);
      // T1 = RY(w1) @ RZ(w0)
      float2 t00 = make_float2(c1 * e0m.x, c1 * e0m.y);
      float2 t01 = make_float2(-s1 * e0p.x, -s1 * e0p.y);
      float2 t10 = make_float2(s1 * e0m.x, s1 * e0m.y);
      float2 t11 = make_float2(c1 * e0p.x, c1 * e0p.y);
      // U = RZ(w2) @ T1
      float2 u00 = cmul(e2m, t00), u01 = cmul(e2m, t01);
      float2 u10 = cmul(e2p, t10), u11 = cmul(e2p, t11);
      float* o = uw + tid * 8;
      o[0] = u00.x; o[1] = u00.y; o[2] = u01.x; o[3] = u01.y;
      o[4] = u10.x; o[5] = u10.y; o[6] = u11.x; o[7] = u11.y;
    }
  } else if (bid <= 9238) {               // bkp = Wk @ proj_b + bk
    int o = (bid - 9237) * 256 + tid;
    if (o < E_) {
      float acc = ipb[E_ + o];
      for (int e = 0; e < E_; ++e) acc += ipw[(size_t)(E_ + o) * E_ + e] * projb[e];
      bkp[o] = acc;
    }
  } else if (bid <= 9240) {               // bvp = Wv @ proj_b + bv
    int o = (bid - 9239) * 256 + tid;
    if (o < E_) {
      float acc = ipb[2 * E_ + o];
      for (int e = 0; e < E_; ++e) acc += ipw[(size_t)(2 * E_ + o) * E_ + e] * projb[e];
      bvp[o] = acc;
    }
  } else {                                // sentinel-fill hs[1..256]
    u32 u = (u32)(bid - 9241) * 256u + tid;  // < 4194304 uint4 units
    ((uint4*)(hs + (size_t)B_ * H_))[u] =
        make_uint4(SENT, SENT, SENT, SENT);
  }
}

// ---------------------------------------------------------------------------
// prep2: Wk' = Wk @ proj_W, Wv' = Wv @ proj_W  (each 320x256)
// ---------------------------------------------------------------------------
__global__ void k_prep2(const float* __restrict__ ipw, const float* __restrict__ projW,
                        float* __restrict__ Wkp, float* __restrict__ Wvp) {
  int bid = blockIdx.x, tid = threadIdx.x;
  int o = (bid < 320) ? bid : (bid - 320);
  const float* wrow = ipw + (size_t)((bid < 320 ? E_ : 2 * E_) + o) * E_;
  float acc = 0.f;
  for (int e = 0; e < E_; ++e) acc += wrow[e] * projW[(size_t)e * H_ + tid];
  (bid < 320 ? Wkp : Wvp)[(size_t)o * H_ + tid] = acc;
}

// ---------------------------------------------------------------------------
// prep3: WuT[e][j] = sum_o Wkp[o][j]*Wq[o][e];  Wovt[j][i] = sum_o Wo[i][o]*Wvp[o][j]
// plus bu, wd, dd, bov
// ---------------------------------------------------------------------------
__global__ void k_prep3(const float* __restrict__ ipw, const float* __restrict__ ipb,
                        const float* __restrict__ opw, const float* __restrict__ opb,
                        const float* __restrict__ Wkp, const float* __restrict__ Wvp,
                        const float* __restrict__ bkp, const float* __restrict__ bvp,
                        float* __restrict__ WuT, float* __restrict__ bu,
                        float* __restrict__ wd, float* __restrict__ ddp,
                        float* __restrict__ Wovt, float* __restrict__ bov) {
  int bid = blockIdx.x, tid = threadIdx.x;
  if (bid < 320) {
    int e = bid;
    float acc = 0.f;
    for (int o = 0; o < E_; ++o) acc += Wkp[(size_t)o * H_ + tid] * ipw[(size_t)o * E_ + e];
    WuT[(size_t)e * H_ + tid] = acc;
  } else if (bid < 576) {
    int jj = bid - 320;
    for (int i = tid; i < E_; i += 256) {
      float acc = 0.f;
      for (int o = 0; o < E_; ++o) acc += opw[(size_t)i * E_ + o] * Wvp[(size_t)o * H_ + jj];
      Wovt[(size_t)jj * E_ + i] = acc;
    }
  } else {
    {
      float acc = 0.f;
      for (int o = 0; o < E_; ++o) acc += Wkp[(size_t)o * H_ + tid] * ipb[o];
      bu[tid] = acc;
    }
    for (int idx = tid; idx < E_; idx += 256) {
      float a1 = 0.f, a2 = opb[idx];
      for (int o = 0; o < E_; ++o) {
        a1 += ipw[(size_t)o * E_ + idx] * bkp[o];
        a2 += opw[(size_t)idx * E_ + o] * bvp[o];
      }
      wd[idx] = a1; bov[idx] = a2;
    }
    if (tid == 0) {
      float acc = 0.f;
      for (int o = 0; o < E_; ++o) acc += ipb[o] * bkp[o];
      ddp[0] = acc;
    }
  }
}

// ---------------------------------------------------------------------------
// LSTM persistent kernel — R0's proven body; sync = throttle + sentinel.
// The R0 chain (drain->signal->detect->load, ~4 MALL round trips, 3.44us/step)
// is shortened by splitting ROLES: the counter provides only LOCKSTEP
// (bounds skew; its absence caused R3's poll runaway), while DATA VALIDITY
// comes from R3's proven per-chunk sentinel check. This permits:
//   raw s_barrier (no vmcnt(0) drain before the signal)  [-1 round trip]
//   fire-and-forget atomicAdd (result unused, no ack)
//   h(t+1) loads issued right after the signal, flight overlapped with the
//   poll window                                           [-1 round trip]
//   acquire = WAITCHUNK sentinel verify interleaved with the h-MFMAs next
//   iteration (usually passes on first check).
// ---------------------------------------------------------------------------
struct LstmArgs {
  const u16* xbf; u16* hs; const u16* Wg; const float* bb; u32* cnt;
};

__launch_bounds__(256, 1)
__global__ void k_lstm(LstmArgs A) {
  const int g   = blockIdx.x & 7;
  const int n   = blockIdx.x >> 3;            // 0..31
  const int tid = threadIdx.x;
  const int wid = tid >> 6, lane = tid & 63;
  __shared__ __align__(16) u16 Wl[32 * 392];  // 32 gate rows x 384 K, pad to 392

  for (int idx = tid; idx < 32 * 48; idx += 256) {
    int ln = idx / 48, c8 = idx % 48;
    int gr = (ln >> 3) * 256 + n * 8 + (ln & 7);
    *(uint4*)&Wl[ln * 392 + c8 * 8] = *(const uint4*)&A.Wg[(size_t)gr * 384 + c8 * 8];
  }
  const int j  = lane & 7;
  const int gc = n * 8 + j;
  const float bbi = A.bb[gc], bbf2 = A.bb[256 + gc];
  const float bbg = A.bb[512 + gc], bbo = A.bb[768 + gc];

  const int quad = lane >> 4;
  const int mrow = lane & 15;
  const int brow = g * 64 + wid * 16 + mrow;
  const int erow0 = g * 64 + wid * 16 + quad * 4;
  const bool hi = (lane & 8) != 0;
  float crs[4] = {0.f, 0.f, 0.f, 0.f};
  u32* const mycnt = A.cnt + g * 64;

  const v4i hs_srd = make_srd(A.hs);
  const int hvoff = (brow * H_ + quad * 8) * 2;   // per-lane byte offset in a step-block

  // prologue: x[0]
  uint4 xc0, xc1, xc2, xc3, xn0, xn1, xn2, xn3;
  {
    const u16* xb = A.xbf + ((size_t)0 * B_ + brow) * DIN + quad * 8;
    xc0 = *(const uint4*)(xb + 0);
    xc1 = *(const uint4*)(xb + 32);
    xc2 = *(const uint4*)(xb + 64);
    xc3 = *(const uint4*)(xb + 96);
  }

#define LOADH(HSOFF)                                                                                        \
    h0 = __builtin_bit_cast(uint4, llvm_amdgcn_raw_buffer_load_v4i32(hs_srd, hvoff +   0, (HSOFF), 17));    \
    h1 = __builtin_bit_cast(uint4, llvm_amdgcn_raw_buffer_load_v4i32(hs_srd, hvoff +  64, (HSOFF), 17));    \
    h2 = __builtin_bit_cast(uint4, llvm_amdgcn_raw_buffer_load_v4i32(hs_srd, hvoff + 128, (HSOFF), 17));    \
    h3 = __builtin_bit_cast(uint4, llvm_amdgcn_raw_buffer_load_v4i32(hs_srd, hvoff + 192, (HSOFF), 17));    \
    h4 = __builtin_bit_cast(uint4, llvm_amdgcn_raw_buffer_load_v4i32(hs_srd, hvoff + 256, (HSOFF), 17));    \
    h5 = __builtin_bit_cast(uint4, llvm_amdgcn_raw_buffer_load_v4i32(hs_srd, hvoff + 320, (HSOFF), 17));    \
    h6 = __builtin_bit_cast(uint4, llvm_amdgcn_raw_buffer_load_v4i32(hs_srd, hvoff + 384, (HSOFF), 17));    \
    h7 = __builtin_bit_cast(uint4, llvm_amdgcn_raw_buffer_load_v4i32(hs_srd, hvoff + 448, (HSOFF), 17));

#define CHK4(v) (((v).x == SENT) | ((v).y == SENT) | ((v).z == SENT) | ((v).w == SENT))

// usually passes the first check (lockstep throttle + poll-window flight);
// retry loop is the rare-path safety net (proven R3)
#define WAITCHUNK(HK, OFF)                                                            \
    {                                                                                 \
      int gd = 0;                                                                     \
      while (__any((int)CHK4(HK))) {                                                  \
        if (++gd > (1 << 22)) break;                                                  \
        __builtin_amdgcn_s_sleep(1);                                                  \
        asm volatile("" ::: "memory");                                                \
        HK = __builtin_bit_cast(uint4,                                                \
            llvm_amdgcn_raw_buffer_load_v4i32(hs_srd, hvoff + (OFF), hsoff, 17));     \
      }                                                                               \
    }

#define MMSTEP(AV, KOFF)                                                          \
    {                                                                             \
      short8 av  = __builtin_bit_cast(short8, AV);                                \
      short8 bv0 = __builtin_bit_cast(short8,                                     \
          *(const uint4*)&Wl[mrow * 392 + (KOFF) + quad * 8]);                    \
      short8 bv1 = __builtin_bit_cast(short8,                                     \
          *(const uint4*)&Wl[(16 + mrow) * 392 + (KOFF) + quad * 8]);             \
      acc0 = __builtin_amdgcn_mfma_f32_16x16x32_bf16(av, bv0, acc0, 0, 0, 0);     \
      acc1 = __builtin_amdgcn_mfma_f32_16x16x32_bf16(av, bv1, acc1, 0, 0, 0);     \
    }

  // prologue: issue h_0 loads (hs[0] = real zeros from prep1 — no sentinel)
  uint4 h0, h1, h2, h3, h4, h5, h6, h7;
  LOADH(0)
  __syncthreads();  // Wl staged

  for (int t = 0; t < T_; ++t) {
    const int hsoff = t * (B_ * H_ * 2);
    // x[t+1] prefetch (plain cached loads)
    {
      const int tn = (t + 1 < T_) ? (t + 1) : t;
      const u16* xb = A.xbf + ((size_t)tn * B_ + brow) * DIN + quad * 8;
      xn0 = *(const uint4*)(xb + 0);
      xn1 = *(const uint4*)(xb + 32);
      xn2 = *(const uint4*)(xb + 64);
      xn3 = *(const uint4*)(xb + 96);
    }

    f32x4 acc0 = {0.f, 0.f, 0.f, 0.f}, acc1 = {0.f, 0.f, 0.f, 0.f};
    // x-part first: independent of h_t
    MMSTEP(xc0, 0)   MMSTEP(xc1, 32)  MMSTEP(xc2, 64)  MMSTEP(xc3, 96)
    // sentinel acquire, chunk-by-chunk, interleaved with the h-part MFMAs
    WAITCHUNK(h0,   0)  MMSTEP(h0, 128)
    WAITCHUNK(h1,  64)  MMSTEP(h1, 160)
    WAITCHUNK(h2, 128)  MMSTEP(h2, 192)
    WAITCHUNK(h3, 192)  MMSTEP(h3, 224)
    WAITCHUNK(h4, 256)  MMSTEP(h4, 256)
    WAITCHUNK(h5, 320)  MMSTEP(h5, 288)
    WAITCHUNK(h6, 384)  MMSTEP(h6, 320)
    WAITCHUNK(h7, 448)  MMSTEP(h7, 352)

    // epilogue: lanes bit3=0 hold i (tile0) & g (tile1); bit3=1 hold f & o
    const int hsoff_o = hsoff + (B_ * H_ * 2);
#pragma unroll
    for (int r = 0; r < 4; ++r) {
      float x0 = acc0[r], x1v = acc1[r];
      float y0 = __shfl_xor(x0, 8, 64);
      float y1 = __shfl_xor(x1v, 8, 64);
      float iv = (hi ? y0 : x0) + bbi;
      float fv = (hi ? x0 : y0) + bbf2;
      float gv = (hi ? y1 : x1v) + bbg;
      float ov = (hi ? x1v : y1) + bbo;
      float cc = sigf(fv) * crs[r] + sigf(iv) * tanhfast(gv);
      crs[r] = cc;
      float hh = sigf(ov) * tanhfast(cc);
      float hh2 = __shfl_xor(hh, 1, 64);      // partner column's h
      if (!hi && ((j & 1) == 0)) {
        u32 pk = (u32)f2b(hh) | ((u32)f2b(hh2) << 16);
        llvm_amdgcn_raw_buffer_store_i32((int)pk, hs_srd,
                                         ((erow0 + r) * H_ + gc) * 2, hsoff_o, 17);
      }
    }

    // ---- lockstep throttle + optimistic next-step loads ----
    if (t != T_ - 1) {
      __builtin_amdgcn_s_barrier();          // raw: no vmcnt(0) drain
      if (tid == 0) {
        __hip_atomic_fetch_add(mycnt, 1u, __ATOMIC_RELAXED,
                               __HIP_MEMORY_SCOPE_AGENT);   // fire-and-forget
      }
      LOADH(hsoff_o)                         // flight overlaps the poll window
      if (tid == 0) {
        const u32 tgt = 32u * (u32)(t + 1);
        int guard = 0;
        while (__hip_atomic_load(mycnt, __ATOMIC_RELAXED,
                                 __HIP_MEMORY_SCOPE_AGENT) < tgt) {
          __builtin_amdgcn_s_sleep(1);
          if (++guard > (1 << 24)) break;
        }
      }
      __builtin_amdgcn_s_barrier();
    }
    xc0 = xn0; xc1 = xn1; xc2 = xn2; xc3 = xn3;
  }
#undef LOADH
#undef CHK4
#undef WAITCHUNK
#undef MMSTEP
}

// ---------------------------------------------------------------------------
// k_u: u_b = WuT^T-style matvec on z=[h_T, s];  d_b = wd.z + dd
// ---------------------------------------------------------------------------
__global__ void k_u(const u16* __restrict__ hs, const float* __restrict__ s,
                    const float* __restrict__ WuT, const float* __restrict__ bu,
                    const float* __restrict__ wd, const float* __restrict__ ddp,
                    float* __restrict__ u, float* __restrict__ dvec) {
  int b = blockIdx.x, tid = threadIdx.x;
  __shared__ float z[E_];
  __shared__ float red[256];
  z[tid] = b2f(hs[((size_t)T_ * B_ + b) * H_ + tid]);
  if (tid < F_) z[H_ + tid] = s[(size_t)b * F_ + tid];
  __syncthreads();
  float acc = bu[tid];
  for (int e = 0; e < E_; ++e) acc += WuT[(size_t)e * H_ + tid] * z[e];
  u[(size_t)b * H_ + tid] = acc;
  float p = 0.f;
  for (int e = tid; e < E_; e += 256) p += wd[e] * z[e];
  red[tid] = p;
  __syncthreads();
  for (int s2 = 128; s2 > 0; s2 >>= 1) {
    if (tid < s2) red[tid] += red[tid + s2];
    __syncthreads();
  }
  if (tid == 0) dvec[b] = red[0] + ddp[0];
}

// ---------------------------------------------------------------------------
// k_aw: scores -> softmax -> w_b = sum_t attn_t * h_t   (block per batch row)
// ---------------------------------------------------------------------------
__global__ void k_aw(const u16* __restrict__ hs, const float* __restrict__ u,
                     const float* __restrict__ dvec, float* __restrict__ wv) {
  int b = blockIdx.x, tid = threadIdx.x;
  int wid = tid >> 6, lane = tid & 63;
  __shared__ float sc[T_];
  __shared__ float red[256];
  const float db = dvec[b];
  const float scale = 0.055901699437494745f;  // 1/sqrt(320)
  float4 ul = *(const float4*)&u[(size_t)b * H_ + lane * 4];
  for (int tt = 0; tt < 64; ++tt) {
    int t = wid * 64 + tt;
    u32 rw0 = ((const u32*)(hs + ((size_t)(t + 1) * B_ + b) * H_))[lane * 2];
    u32 rw1 = ((const u32*)(hs + ((size_t)(t + 1) * B_ + b) * H_))[lane * 2 + 1];
    union { u32 uu; float f; } f0, f1, f2, f3;
    f0.uu = rw0 << 16; f1.uu = rw0 & 0xFFFF0000u;
    f2.uu = rw1 << 16; f3.uu = rw1 & 0xFFFF0000u;
    float p = f0.f * ul.x + f1.f * ul.y + f2.f * ul.z + f3.f * ul.w;
#pragma unroll
    for (int off = 32; off > 0; off >>= 1) p += __shfl_xor(p, off, 64);
    if (lane == 0) sc[t] = (p + db) * scale;
  }
  __syncthreads();
  float v = sc[tid];
  red[tid] = v;
  __syncthreads();
  for (int s2 = 128; s2 > 0; s2 >>= 1) {
    if (tid < s2) red[tid] = fmaxf(red[tid], red[tid + s2]);
    __syncthreads();
  }
  float m = red[0];
  __syncthreads();
  float e = __expf(v - m);
  red[tid] = e;
  __syncthreads();
  for (int s2 = 128; s2 > 0; s2 >>= 1) {
    if (tid < s2) red[tid] += red[tid + s2];
    __syncthreads();
  }
  float inv = 1.f / red[0];
  __syncthreads();
  sc[tid] = e * inv;
  __syncthreads();
  float acc = 0.f;
#pragma unroll 8
  for (int t = 0; t < T_; ++t) {
    acc += sc[t] * b2f(hs[((size_t)(t + 1) * B_ + b) * H_ + tid]);
  }
  wv[(size_t)b * H_ + tid] = acc;
}

// ---------------------------------------------------------------------------
// k_ao: merged_state = [Wov @ w_b + bov, s_b]
// ---------------------------------------------------------------------------
__global__ void k_ao(const float* __restrict__ wv, const float* __restrict__ Wovt,
                     const float* __restrict__ bov, const float* __restrict__ s,
                     float* __restrict__ mst) {
  int b = blockIdx.x, tid = threadIdx.x;
  __shared__ float wl[H_];
  if (tid < H_) wl[tid] = wv[(size_t)b * H_ + tid];
  __syncthreads();
  if (tid < E_) {
    float acc = bov[tid];
    for (int jj = 0; jj < H_; ++jj) acc += Wovt[(size_t)jj * E_ + tid] * wl[jj];
    mst[(size_t)b * DM + tid] = acc;
  } else if (tid < DM) {
    mst[(size_t)b * DM + tid] = s[(size_t)b * F_ + (tid - E_)];
  }
}

// ---------------------------------------------------------------------------
// k_vqc: 10-qubit statevector sim; 1 combined gate per (layer,qubit); psi in LDS
// ---------------------------------------------------------------------------
__global__ void k_vqc(const float* __restrict__ mst, const float* __restrict__ uwg,
                      float* __restrict__ qf) {
  int b = blockIdx.x, tid = threadIdx.x;
  __shared__ float2 psi[1024];
  __shared__ float ang[40];
  __shared__ float uwl[320];
  __shared__ float part[4][10];
  if (tid < 40) ang[tid] = tanhf(mst[(size_t)b * DM + tid]) * PI_F;
  uwl[tid] = uwg[tid];
  if (tid < 64) uwl[256 + tid] = uwg[256 + tid];
#pragma unroll
  for (int k = 0; k < 4; ++k) psi[tid + k * 256] = make_float2(0.03125f, 0.f);
  __syncthreads();
  for (int l = 0; l < 4; ++l) {
    for (int q = 0; q < 10; ++q) {
      int lq = l * 10 + q;
      float a = ang[lq];
      float ca = __cosf(0.5f * a), sa = __sinf(0.5f * a);
      float cs = ca * sa;
      float2 m00 = make_float2(ca * ca, sa * sa);
      float2 m01 = make_float2(-cs, -cs);
      float2 m10 = make_float2(cs, -cs);
      float2 m11 = make_float2(ca * ca, -sa * sa);
      const float* uwp = &uwl[lq * 8];
      float2 a00 = make_float2(uwp[0], uwp[1]), a01 = make_float2(uwp[2], uwp[3]);
      float2 a10 = make_float2(uwp[4], uwp[5]), a11 = make_float2(uwp[6], uwp[7]);
      float2 u00 = cadd(cmul(a00, m00), cmul(a01, m10));
      float2 u01 = cadd(cmul(a00, m01), cmul(a01, m11));
      float2 u10 = cadd(cmul(a10, m00), cmul(a11, m10));
      float2 u11 = cadd(cmul(a10, m01), cmul(a11, m11));
      int bp = 9 - q;
      __syncthreads();
#pragma unroll
      for (int k = 0; k < 2; ++k) {
        int p = tid + k * 256;
        int i0 = ((p >> bp) << (bp + 1)) | (p & ((1 << bp) - 1));
        int i1 = i0 | (1 << bp);
        float2 A0 = psi[i0], A1 = psi[i1];
        psi[i0] = cadd(cmul(u00, A0), cmul(u01, A1));
        psi[i1] = cadd(cmul(u10, A0), cmul(u11, A1));
      }
    }
    for (int q = 0; q < 9; ++q) {  // CNOT(q, q+1): adjacent bits
      int lo = 8 - q;
      __syncthreads();
      int p = tid;
      int i0 = ((p >> lo) << (lo + 2)) | (2 << lo) | (p & ((1 << lo) - 1));
      int i1 = i0 | (1 << lo);
      float2 tmp = psi[i0]; psi[i0] = psi[i1]; psi[i1] = tmp;
    }
    __syncthreads();  // CNOT(9, 0): ctrl bit0, tgt bit9
    {
      int i0 = (tid << 1) | 1;
      int i1 = i0 | 512;
      float2 tmp = psi[i0]; psi[i0] = psi[i1]; psi[i1] = tmp;
    }
  }
  __syncthreads();
  float acc[10];
#pragma unroll
  for (int q = 0; q < 10; ++q) acc[q] = 0.f;
#pragma unroll
  for (int k = 0; k < 4; ++k) {
    int idx = tid + k * 256;
    float2 A = psi[idx];
    float pr = A.x * A.x + A.y * A.y;
#pragma unroll
    for (int q = 0; q < 10; ++q) acc[q] += ((idx >> (9 - q)) & 1) ? -pr : pr;
  }
  int lane = tid & 63, wid = tid >> 6;
#pragma unroll
  for (int q = 0; q < 10; ++q) {
    float vq = acc[q];
#pragma unroll
    for (int off = 32; off > 0; off >>= 1) vq += __shfl_xor(vq, off, 64);
    if (lane == 0) part[wid][q] = vq;
  }
  __syncthreads();
  if (tid < 10) qf[(size_t)b * 10 + tid] = part[0][tid] + part[1][tid] + part[2][tid] + part[3][tid];
}

// ---------------------------------------------------------------------------
// k_mlp: x1 = relu([mst,qf] @ W1^T + b1); out = x1 @ W2^T + b2
// ---------------------------------------------------------------------------
__global__ void k_mlp(const float* __restrict__ mst, const float* __restrict__ qf,
                      const float* __restrict__ W1t, const float* __restrict__ b1,
                      const float* __restrict__ W2, const float* __restrict__ b2,
                      float* __restrict__ out) {
  int b = blockIdx.x, tid = threadIdx.x;
  __shared__ float mg[KMLP];
  __shared__ float x1[NL1];
  __shared__ float red[256];
  for (int i = tid; i < DM; i += 256) mg[i] = mst[(size_t)b * DM + i];
  if (tid < 10) mg[DM + tid] = qf[(size_t)b * 10 + tid];
  __syncthreads();
#pragma unroll
  for (int hh = 0; hh < 2; ++hh) {
    int nn = tid + hh * 256;
    float acc = b1[nn];
#pragma unroll 4
    for (int k = 0; k < KMLP; ++k) acc += W1t[(size_t)k * NL1 + nn] * mg[k];
    x1[nn] = fmaxf(acc, 0.f);
  }
  __syncthreads();
  int a = tid >> 5, l32 = tid & 31;
  float p = 0.f;
  for (int k = l32; k < NL1; k += 32) p += x1[k] * W2[(size_t)a * NL1 + k];
  red[tid] = p;
  __syncthreads();
  if (tid < 8) {
    float acc = b2[tid];
#pragma unroll
    for (int i = 0; i < 32; ++i) acc += red[tid * 32 + i];
    out[(size_t)b * NACT + tid] = acc;
  }
}

// ---------------------------------------------------------------------------
extern "C" void kernel_launch(void* const* d_in, const int* in_sizes, int n_in,
                              void* d_out, int out_size, void* d_ws, size_t ws_size,
                              hipStream_t stream) {
  const float* s      = (const float*)d_in[0];
  const float* lstm_s = (const float*)d_in[1];
  const float* W_ih   = (const float*)d_in[2];
  const float* W_hh   = (const float*)d_in[3];
  const float* b_ih   = (const float*)d_in[4];
  const float* b_hh   = (const float*)d_in[5];
  const float* projW  = (const float*)d_in[6];
  const float* projb  = (const float*)d_in[7];
  const float* ipw    = (const float*)d_in[8];
  const float* ipb    = (const float*)d_in[9];
  const float* opw    = (const float*)d_in[10];
  const float* opb    = (const float*)d_in[11];
  const float* qw     = (const float*)d_in[12];
  const float* W1     = (const float*)d_in[13];
  const float* b1     = (const float*)d_in[14];
  const float* W2     = (const float*)d_in[15];
  const float* b2     = (const float*)d_in[16];
  float* out = (float*)d_out;

  char* wsb = (char*)d_ws;
  size_t off = 0;
  auto alloc = [&](size_t bytes) -> void* {
    void* p = wsb + off;
    off = (off + bytes + 255) & ~(size_t)255;
    return p;
  };
  u16*  xbf  = (u16*)alloc((size_t)T_ * B_ * DIN * 2);
  u16*  hs   = (u16*)alloc((size_t)(T_ + 1) * B_ * H_ * 2);
  u16*  Wg   = (u16*)alloc((size_t)G4 * 384 * 2);
  float* bb  = (float*)alloc(G4 * 4);
  float* Wkp = (float*)alloc((size_t)E_ * H_ * 4);
  float* Wvp = (float*)alloc((size_t)E_ * H_ * 4);
  float* bkp = (float*)alloc(E_ * 4);
  float* bvp = (float*)alloc(E_ * 4);
  float* WuT = (float*)alloc((size_t)E_ * H_ * 4);
  float* bu  = (float*)alloc(H_ * 4);
  float* wd  = (float*)alloc(E_ * 4);
  float* ddp = (float*)alloc(256);
  float* Wovt= (float*)alloc((size_t)H_ * E_ * 4);
  float* bov = (float*)alloc(E_ * 4);
  float* uu  = (float*)alloc((size_t)B_ * H_ * 4);
  float* dvec= (float*)alloc(B_ * 4);
  float* wv  = (float*)alloc((size_t)B_ * H_ * 4);
  float* mst = (float*)alloc((size_t)B_ * DM * 4);
  float* qf  = (float*)alloc((size_t)B_ * 10 * 4);
  float* uw  = (float*)alloc(40 * 8 * 4);
  float* W1t = (float*)alloc((size_t)KMLP * NL1 * 4);
  u32*  cnt  = (u32*)alloc(1024 * 4);
  (void)ws_size; (void)in_sizes; (void)n_in; (void)out_size;

  hipLaunchKernelGGL(k_prep1, dim3(25625), dim3(256), 0, stream,
                     lstm_s, W_ih, W_hh, b_ih, b_hh, ipw, ipb, projb, qw, W1,
                     xbf, hs, Wg, bb, W1t, uw, bkp, bvp, cnt);
  hipLaunchKernelGGL(k_prep2, dim3(640), dim3(256), 0, stream, ipw, projW, Wkp, Wvp);
  hipLaunchKernelGGL(k_prep3, dim3(577), dim3(256), 0, stream,
                     ipw, ipb, opw, opb, Wkp, Wvp, bkp, bvp, WuT, bu, wd, ddp, Wovt, bov);

  LstmArgs la;
  la.xbf = xbf; la.hs = hs; la.Wg = Wg; la.bb = bb; la.cnt = cnt;
  void* kargs[] = { (void*)&la };
  hipError_t ce = hipLaunchCooperativeKernel(reinterpret_cast<const void*>(&k_lstm),
                                             dim3(256), dim3(256), kargs, 0, stream);
  if (ce != hipSuccess) {
    // fallback: plain launch (256 blocks on 256 CUs co-schedule in practice)
    hipLaunchKernelGGL(k_lstm, dim3(256), dim3(256), 0, stream, la);
  }

  hipLaunchKernelGGL(k_u,   dim3(512), dim3(256), 0, stream, hs, s, WuT, bu, wd, ddp, uu, dvec);
  hipLaunchKernelGGL(k_aw,  dim3(512), dim3(256), 0, stream, hs, uu, dvec, wv);
  hipLaunchKernelGGL(k_ao,  dim3(512), dim3(384), 0, stream, wv, Wovt, bov, s, mst);
  hipLaunchKernelGGL(k_vqc, dim3(512), dim3(256), 0, stream, mst, uw, qf);
  hipLaunchKernelGGL(k_mlp, dim3(512), dim3(256), 0, stream, mst, qf, W1t, b1, W2, b2, out);
}

// Round 7
// 1294.704 us; speedup vs baseline: 2.2365x; 2.2365x over previous
//
#include <hip/hip_runtime.h>
#include <hip/hip_bf16.h>
#include <math.h>

typedef unsigned int u32;
typedef unsigned long long u64;
typedef unsigned short u16;
typedef __attribute__((ext_vector_type(8))) short short8;
typedef __attribute__((ext_vector_type(4))) float f32x4;
typedef __attribute__((ext_vector_type(4))) int v4i;

#define PI_F 3.14159265358979f
#define B_   512
#define T_   256
#define DIN  128
#define H_   256
#define G4   1024
#define F_   64
#define E_   320
#define DM   384
#define NL1  512
#define NACT 8
#define KMLP 394

// Raw buffer intrinsics (CK idiom): compiler-known memory ops (auto waitcnt,
// free pipelining) with explicit cache policy. aux=17 = sc0|sc1: bypass
// L1+L2, read/write at the device coherence point (MALL). The ONLY scope
// proven (R0-R6) for cross-block store->load visibility. R0's barrier
// (syncthreads-drain -> agent atomicAdd -> tid0 poll -> syncthreads) is the
// empirical optimum: every alternative tried (sentinel dataflow R1/R3/R6,
// SC0-only R2, per-wave flags R4, sharded counters R5, optimistic loads R6)
// measured worse. 3.44us/step ≈ 3 serial MALL round trips + compute.
__device__ v4i llvm_amdgcn_raw_buffer_load_v4i32(v4i rsrc, int voffset,
                                                 int soffset, int aux)
    __asm("llvm.amdgcn.raw.buffer.load.v4i32");
__device__ void llvm_amdgcn_raw_buffer_store_i32(int vdata, v4i rsrc,
                                                 int voffset, int soffset,
                                                 int aux)
    __asm("llvm.amdgcn.raw.buffer.store.i32");

__device__ __forceinline__ v4i make_srd(const void* p) {
  v4i r;
  r.x = (int)(u32)(u64)p;
  r.y = (int)(u32)((u64)p >> 32);   // base hi, stride=0
  r.z = (int)0xFFFFFFFFu;           // num_records: bounds check disabled
  r.w = 0x00020000;                 // raw untyped dword access
  return r;
}

__device__ __forceinline__ float b2f(u16 h) {
  union { u32 u; float f; } v; v.u = ((u32)h) << 16; return v.f;
}
__device__ __forceinline__ u16 f2b(float f) {
  union { float f; u32 u; } v; v.f = f;
  u32 r = (v.u + 0x7FFFu + ((v.u >> 16) & 1u)) >> 16;
  return (u16)r;
}
__device__ __forceinline__ float sigf(float x) { return 1.0f / (1.0f + __expf(-x)); }
__device__ __forceinline__ float tanhfast(float x) { return 2.0f / (1.0f + __expf(-2.0f * x)) - 1.0f; }
__device__ __forceinline__ float2 cmul(float2 a, float2 b) {
  return make_float2(a.x * b.x - a.y * b.y, a.x * b.y + a.y * b.x);
}
__device__ __forceinline__ float2 cadd(float2 a, float2 b) {
  return make_float2(a.x + b.x, a.y + b.y);
}

// ---------------------------------------------------------------------------
// prep1: x transpose+bf16, Wg=[W_ih|W_hh] bf16, zero hs[0], W1t, bb, uw, bkp,
// bvp, zero barrier counters  (exact R0 version)
// ---------------------------------------------------------------------------
__global__ void k_prep1(const float* __restrict__ lstm_s,
                        const float* __restrict__ W_ih,
                        const float* __restrict__ W_hh,
                        const float* __restrict__ b_ih,
                        const float* __restrict__ b_hh,
                        const float* __restrict__ ipw,
                        const float* __restrict__ ipb,
                        const float* __restrict__ projb,
                        const float* __restrict__ qw,
                        const float* __restrict__ W1,
                        u16* __restrict__ xbf,
                        u16* __restrict__ hs,
                        u16* __restrict__ Wg,
                        float* __restrict__ bb,
                        float* __restrict__ W1t,
                        float* __restrict__ uw,
                        float* __restrict__ bkp,
                        float* __restrict__ bvp,
                        u32* __restrict__ cnt) {
  const int bid = blockIdx.x;
  const int tid = threadIdx.x;
  if (bid < 8192) {                       // lstm_s (B,T,128) -> xbf (T,B,128) bf16
    u32 u = (u32)bid * 256u + tid;        // < 2097152 uint4 units
    u32 c8 = u & 15u, b = (u >> 4) & 511u, t = u >> 13;
    const float* src = lstm_s + ((size_t)b * T_ + t) * DIN + c8 * 8;
    union { u16 h[8]; uint4 v; } tmp;
#pragma unroll
    for (int i = 0; i < 8; ++i) tmp.h[i] = f2b(src[i]);
    *(uint4*)(xbf + ((size_t)t * B_ + b) * DIN + c8 * 8) = tmp.v;
  } else if (bid < 8384) {                // Wg (1024 x 384) bf16
    u32 u = (u32)(bid - 8192) * 256u + tid;  // < 49152
    u32 c8 = u % 48u, r = u / 48u;
    const float* src = (c8 < 16) ? (W_ih + (size_t)r * DIN + c8 * 8)
                                 : (W_hh + (size_t)r * H_ + (c8 - 16) * 8);
    union { u16 h[8]; uint4 v; } tmp;
#pragma unroll
    for (int i = 0; i < 8; ++i) tmp.h[i] = f2b(src[i]);
    *(uint4*)(Wg + (size_t)r * 384 + c8 * 8) = tmp.v;
  } else if (bid < 8448) {                // zero hs[0]
    u32 u = (u32)(bid - 8384) * 256u + tid;  // < 16384
    ((uint4*)hs)[u] = make_uint4(0, 0, 0, 0);
  } else if (bid < 9236) {                // W1t[k][n] = W1[n][k]
    u32 u = (u32)(bid - 8448) * 256u + tid;  // < 201728
    u32 k = u / 512u, nn = u % 512u;
    W1t[u] = W1[(size_t)nn * KMLP + k];
  } else if (bid == 9236) {               // bb, cnt, uw
    for (int i = tid; i < 1024; i += 256) bb[i] = b_ih[i] + b_hh[i];
    for (int i = tid; i < 1024; i += 256) cnt[i] = 0u;
    if (tid < 40) {
      float w0 = qw[tid * 3 + 0], w1 = qw[tid * 3 + 1], w2 = qw[tid * 3 + 2];
      float c0 = cosf(0.5f * w0), s0 = sinf(0.5f * w0);
      float c1 = cosf(0.5f * w1), s1 = sinf(0.5f * w1);
      float c2 = cosf(0.5f * w2), s2 = sinf(0.5f * w2);
      float2 e0m = make_float2(c0, -s0), e0p = make_float2(c0, s0);
      float2 e2m = make_float2(c2, -s2), e2p = make_float2(c2, s2);
      // T1 = RY(w1) @ RZ(w0)
      float2 t00 = make_float2(c1 * e0m.x, c1 * e0m.y);
      float2 t01 = make_float2(-s1 * e0p.x, -s1 * e0p.y);
      float2 t10 = make_float2(s1 * e0m.x, s1 * e0m.y);
      float2 t11 = make_float2(c1 * e0p.x, c1 * e0p.y);
      // U = RZ(w2) @ T1
      float2 u00 = cmul(e2m, t00), u01 = cmul(e2m, t01);
      float2 u10 = cmul(e2p, t10), u11 = cmul(e2p, t11);
      float* o = uw + tid * 8;
      o[0] = u00.x; o[1] = u00.y; o[2] = u01.x; o[3] = u01.y;
      o[4] = u10.x; o[5] = u10.y; o[6] = u11.x; o[7] = u11.y;
    }
  } else if (bid <= 9238) {               // bkp = Wk @ proj_b + bk
    int o = (bid - 9237) * 256 + tid;
    if (o < E_) {
      float acc = ipb[E_ + o];
      for (int e = 0; e < E_; ++e) acc += ipw[(size_t)(E_ + o) * E_ + e] * projb[e];
      bkp[o] = acc;
    }
  } else {                                // bvp = Wv @ proj_b + bv
    int o = (bid - 9239) * 256 + tid;
    if (o < E_) {
      float acc = ipb[2 * E_ + o];
      for (int e = 0; e < E_; ++e) acc += ipw[(size_t)(2 * E_ + o) * E_ + e] * projb[e];
      bvp[o] = acc;
    }
  }
}

// ---------------------------------------------------------------------------
// prep2: Wk' = Wk @ proj_W, Wv' = Wv @ proj_W  (each 320x256)
// ---------------------------------------------------------------------------
__global__ void k_prep2(const float* __restrict__ ipw, const float* __restrict__ projW,
                        float* __restrict__ Wkp, float* __restrict__ Wvp) {
  int bid = blockIdx.x, tid = threadIdx.x;
  int o = (bid < 320) ? bid : (bid - 320);
  const float* wrow = ipw + (size_t)((bid < 320 ? E_ : 2 * E_) + o) * E_;
  float acc = 0.f;
  for (int e = 0; e < E_; ++e) acc += wrow[e] * projW[(size_t)e * H_ + tid];
  (bid < 320 ? Wkp : Wvp)[(size_t)o * H_ + tid] = acc;
}

// ---------------------------------------------------------------------------
// prep3: WuT[e][j] = sum_o Wkp[o][j]*Wq[o][e];  Wovt[j][i] = sum_o Wo[i][o]*Wvp[o][j]
// plus bu, wd, dd, bov
// ---------------------------------------------------------------------------
__global__ void k_prep3(const float* __restrict__ ipw, const float* __restrict__ ipb,
                        const float* __restrict__ opw, const float* __restrict__ opb,
                        const float* __restrict__ Wkp, const float* __restrict__ Wvp,
                        const float* __restrict__ bkp, const float* __restrict__ bvp,
                        float* __restrict__ WuT, float* __restrict__ bu,
                        float* __restrict__ wd, float* __restrict__ ddp,
                        float* __restrict__ Wovt, float* __restrict__ bov) {
  int bid = blockIdx.x, tid = threadIdx.x;
  if (bid < 320) {
    int e = bid;
    float acc = 0.f;
    for (int o = 0; o < E_; ++o) acc += Wkp[(size_t)o * H_ + tid] * ipw[(size_t)o * E_ + e];
    WuT[(size_t)e * H_ + tid] = acc;
  } else if (bid < 576) {
    int jj = bid - 320;
    for (int i = tid; i < E_; i += 256) {
      float acc = 0.f;
      for (int o = 0; o < E_; ++o) acc += opw[(size_t)i * E_ + o] * Wvp[(size_t)o * H_ + jj];
      Wovt[(size_t)jj * E_ + i] = acc;
    }
  } else {
    {
      float acc = 0.f;
      for (int o = 0; o < E_; ++o) acc += Wkp[(size_t)o * H_ + tid] * ipb[o];
      bu[tid] = acc;
    }
    for (int idx = tid; idx < E_; idx += 256) {
      float a1 = 0.f, a2 = opb[idx];
      for (int o = 0; o < E_; ++o) {
        a1 += ipw[(size_t)o * E_ + idx] * bkp[o];
        a2 += opw[(size_t)idx * E_ + o] * bvp[o];
      }
      wd[idx] = a1; bov[idx] = a2;
    }
    if (tid == 0) {
      float acc = 0.f;
      for (int o = 0; o < E_; ++o) acc += ipb[o] * bkp[o];
      ddp[0] = acc;
    }
  }
}

// ---------------------------------------------------------------------------
// LSTM persistent kernel — EXACT R0 body (the proven 3.44us/step optimum).
// 256 blocks = 8 batch-groups(64 rows) x 32 n-slices. Cross-XCD h handoff via
// NON-ATOMIC buffer ops with aux=17 (sc0|sc1 -> coherence point), pipelined
// 8-deep. Barrier: __syncthreads (implicit vmcnt(0) drains h stores + x
// prefetch) + agent-scope counter.
// ---------------------------------------------------------------------------
struct LstmArgs {
  const u16* xbf; u16* hs; const u16* Wg; const float* bb; u32* cnt;
};

__launch_bounds__(256, 1)
__global__ void k_lstm(LstmArgs A) {
  const int g   = blockIdx.x & 7;
  const int n   = blockIdx.x >> 3;            // 0..31
  const int tid = threadIdx.x;
  const int wid = tid >> 6, lane = tid & 63;
  __shared__ __align__(16) u16 Wl[32 * 392];  // 32 gate rows x 384 K, pad to 392

  for (int idx = tid; idx < 32 * 48; idx += 256) {
    int ln = idx / 48, c8 = idx % 48;
    int gr = (ln >> 3) * 256 + n * 8 + (ln & 7);
    *(uint4*)&Wl[ln * 392 + c8 * 8] = *(const uint4*)&A.Wg[(size_t)gr * 384 + c8 * 8];
  }
  const int j  = lane & 7;
  const int gc = n * 8 + j;
  const float bbi = A.bb[gc], bbf2 = A.bb[256 + gc];
  const float bbg = A.bb[512 + gc], bbo = A.bb[768 + gc];

  const int quad = lane >> 4;
  const int mrow = lane & 15;
  const int brow = g * 64 + wid * 16 + mrow;
  const int erow0 = g * 64 + wid * 16 + quad * 4;
  const bool hi = (lane & 8) != 0;
  float crs[4] = {0.f, 0.f, 0.f, 0.f};
  u32* mycnt = A.cnt + g * 64;
  u32 target = 0;

  const v4i hs_srd = make_srd(A.hs);
  const int hvoff = (brow * H_ + quad * 8) * 2;   // per-lane byte offset in a step-block

  // prologue: x[0]
  uint4 xc0, xc1, xc2, xc3, xn0, xn1, xn2, xn3;
  {
    const u16* xb = A.xbf + ((size_t)0 * B_ + brow) * DIN + quad * 8;
    xc0 = *(const uint4*)(xb + 0);
    xc1 = *(const uint4*)(xb + 32);
    xc2 = *(const uint4*)(xb + 64);
    xc3 = *(const uint4*)(xb + 96);
  }
  __syncthreads();  // Wl staged

  for (int t = 0; t < T_; ++t) {
    // h_t loads: coherent (sc0|sc1) pipelined buffer loads
    const int hsoff = t * (B_ * H_ * 2);
    uint4 h0 = __builtin_bit_cast(uint4, llvm_amdgcn_raw_buffer_load_v4i32(hs_srd, hvoff +   0, hsoff, 17));
    uint4 h1 = __builtin_bit_cast(uint4, llvm_amdgcn_raw_buffer_load_v4i32(hs_srd, hvoff +  64, hsoff, 17));
    uint4 h2 = __builtin_bit_cast(uint4, llvm_amdgcn_raw_buffer_load_v4i32(hs_srd, hvoff + 128, hsoff, 17));
    uint4 h3 = __builtin_bit_cast(uint4, llvm_amdgcn_raw_buffer_load_v4i32(hs_srd, hvoff + 192, hsoff, 17));
    uint4 h4 = __builtin_bit_cast(uint4, llvm_amdgcn_raw_buffer_load_v4i32(hs_srd, hvoff + 256, hsoff, 17));
    uint4 h5 = __builtin_bit_cast(uint4, llvm_amdgcn_raw_buffer_load_v4i32(hs_srd, hvoff + 320, hsoff, 17));
    uint4 h6 = __builtin_bit_cast(uint4, llvm_amdgcn_raw_buffer_load_v4i32(hs_srd, hvoff + 384, hsoff, 17));
    uint4 h7 = __builtin_bit_cast(uint4, llvm_amdgcn_raw_buffer_load_v4i32(hs_srd, hvoff + 448, hsoff, 17));
    // x[t+1] prefetch (plain cached loads; drained by the barrier's vmcnt(0))
    {
      const int tn = (t + 1 < T_) ? (t + 1) : t;
      const u16* xb = A.xbf + ((size_t)tn * B_ + brow) * DIN + quad * 8;
      xn0 = *(const uint4*)(xb + 0);
      xn1 = *(const uint4*)(xb + 32);
      xn2 = *(const uint4*)(xb + 64);
      xn3 = *(const uint4*)(xb + 96);
    }

    f32x4 acc0 = {0.f, 0.f, 0.f, 0.f}, acc1 = {0.f, 0.f, 0.f, 0.f};
#define MMSTEP(AV, KOFF)                                                          \
    {                                                                             \
      short8 av  = __builtin_bit_cast(short8, AV);                                \
      short8 bv0 = __builtin_bit_cast(short8,                                     \
          *(const uint4*)&Wl[mrow * 392 + (KOFF) + quad * 8]);                    \
      short8 bv1 = __builtin_bit_cast(short8,                                     \
          *(const uint4*)&Wl[(16 + mrow) * 392 + (KOFF) + quad * 8]);             \
      acc0 = __builtin_amdgcn_mfma_f32_16x16x32_bf16(av, bv0, acc0, 0, 0, 0);     \
      acc1 = __builtin_amdgcn_mfma_f32_16x16x32_bf16(av, bv1, acc1, 0, 0, 0);     \
    }
    MMSTEP(xc0, 0)   MMSTEP(xc1, 32)  MMSTEP(xc2, 64)  MMSTEP(xc3, 96)
    MMSTEP(h0, 128)  MMSTEP(h1, 160)  MMSTEP(h2, 192)  MMSTEP(h3, 224)
    MMSTEP(h4, 256)  MMSTEP(h5, 288)  MMSTEP(h6, 320)  MMSTEP(h7, 352)
#undef MMSTEP

    // epilogue: lanes bit3=0 hold i (tile0) & g (tile1); bit3=1 hold f & o
    const int hsoff_o = (t + 1) * (B_ * H_ * 2);
#pragma unroll
    for (int r = 0; r < 4; ++r) {
      float x0 = acc0[r], x1v = acc1[r];
      float y0 = __shfl_xor(x0, 8, 64);
      float y1 = __shfl_xor(x1v, 8, 64);
      float iv = (hi ? y0 : x0) + bbi;
      float fv = (hi ? x0 : y0) + bbf2;
      float gv = (hi ? y1 : x1v) + bbg;
      float ov = (hi ? x1v : y1) + bbo;
      float cc = sigf(fv) * crs[r] + sigf(iv) * tanhfast(gv);
      crs[r] = cc;
      float hh = sigf(ov) * tanhfast(cc);
      float hh2 = __shfl_xor(hh, 1, 64);      // partner column's h
      if (!hi && ((j & 1) == 0)) {
        u32 pk = (u32)f2b(hh) | ((u32)f2b(hh2) << 16);
        llvm_amdgcn_raw_buffer_store_i32((int)pk, hs_srd,
                                         ((erow0 + r) * H_ + gc) * 2, hsoff_o, 17);
      }
    }
    // ---- group barrier (release h_t, acquire peers' h_t) ----
    target += 32;
    if (t != T_ - 1) {
      __syncthreads();   // implicit vmcnt(0): h stores at MALL, x prefetch done
      if (tid == 0) {
        __hip_atomic_fetch_add(mycnt, 1u, __ATOMIC_RELAXED, __HIP_MEMORY_SCOPE_AGENT);
        int guard = 0;
        while (__hip_atomic_load(mycnt, __ATOMIC_RELAXED, __HIP_MEMORY_SCOPE_AGENT) < target) {
          __builtin_amdgcn_s_sleep(1);
          if (++guard > (1 << 24)) break;
        }
      }
      __syncthreads();
      xc0 = xn0; xc1 = xn1; xc2 = xn2; xc3 = xn3;
    }
  }
}

// ---------------------------------------------------------------------------
// k_post: fused tail — per batch row b: u/d (k_u) -> scores/softmax/wv (k_aw)
// -> merged_state (k_ao) -> VQC (k_vqc) -> MLP (k_mlp). All five stages are
// per-batch-row independent with a pure block-b -> block-b chain, so they fuse
// into one kernel with LDS intermediates (uu/wv/mst/qf never touch global).
// Eliminates 4 kernel launches + 4 global round-trips. Bodies unchanged.
// ---------------------------------------------------------------------------
__global__ void k_post(const u16* __restrict__ hs, const float* __restrict__ s,
                       const float* __restrict__ WuT, const float* __restrict__ bu,
                       const float* __restrict__ wd, const float* __restrict__ ddp,
                       const float* __restrict__ Wovt, const float* __restrict__ bov,
                       const float* __restrict__ uwg,
                       const float* __restrict__ W1t, const float* __restrict__ b1,
                       const float* __restrict__ W2, const float* __restrict__ b2,
                       float* __restrict__ out) {
  int b = blockIdx.x, tid = threadIdx.x;
  int wid = tid >> 6, lane = tid & 63;
  __shared__ float z[E_];
  __shared__ float red[256];
  __shared__ float ul_s[H_];
  __shared__ float sc[T_];
  __shared__ float wv_s[H_];
  __shared__ float mst_l[DM];
  __shared__ float dvec_s;
  __shared__ float2 psi[1024];
  __shared__ float ang[40];
  __shared__ float uwl[320];
  __shared__ float part[4][10];
  __shared__ float qf_s[10];
  __shared__ float mg[KMLP];
  __shared__ float x1[NL1];

  // ---- phase A (k_u): u_b and d_b ----
  z[tid] = b2f(hs[((size_t)T_ * B_ + b) * H_ + tid]);
  if (tid < F_) z[H_ + tid] = s[(size_t)b * F_ + tid];
  __syncthreads();
  {
    float acc = bu[tid];
    for (int e = 0; e < E_; ++e) acc += WuT[(size_t)e * H_ + tid] * z[e];
    ul_s[tid] = acc;
    float p = 0.f;
    for (int e = tid; e < E_; e += 256) p += wd[e] * z[e];
    red[tid] = p;
    __syncthreads();
    for (int s2 = 128; s2 > 0; s2 >>= 1) {
      if (tid < s2) red[tid] += red[tid + s2];
      __syncthreads();
    }
    if (tid == 0) dvec_s = red[0] + ddp[0];
    __syncthreads();
  }

  // ---- phase B (k_aw): scores -> softmax -> wv ----
  {
    const float db = dvec_s;
    const float scale = 0.055901699437494745f;  // 1/sqrt(320)
    float4 ul = make_float4(ul_s[lane * 4], ul_s[lane * 4 + 1],
                            ul_s[lane * 4 + 2], ul_s[lane * 4 + 3]);
    for (int tt = 0; tt < 64; ++tt) {
      int t = wid * 64 + tt;
      u32 rw0 = ((const u32*)(hs + ((size_t)(t + 1) * B_ + b) * H_))[lane * 2];
      u32 rw1 = ((const u32*)(hs + ((size_t)(t + 1) * B_ + b) * H_))[lane * 2 + 1];
      union { u32 uu; float f; } f0, f1, f2, f3;
      f0.uu = rw0 << 16; f1.uu = rw0 & 0xFFFF0000u;
      f2.uu = rw1 << 16; f3.uu = rw1 & 0xFFFF0000u;
      float p = f0.f * ul.x + f1.f * ul.y + f2.f * ul.z + f3.f * ul.w;
#pragma unroll
      for (int off = 32; off > 0; off >>= 1) p += __shfl_xor(p, off, 64);
      if (lane == 0) sc[t] = (p + db) * scale;
    }
    __syncthreads();
    float v = sc[tid];
    red[tid] = v;
    __syncthreads();
    for (int s2 = 128; s2 > 0; s2 >>= 1) {
      if (tid < s2) red[tid] = fmaxf(red[tid], red[tid + s2]);
      __syncthreads();
    }
    float m = red[0];
    __syncthreads();
    float e = __expf(v - m);
    red[tid] = e;
    __syncthreads();
    for (int s2 = 128; s2 > 0; s2 >>= 1) {
      if (tid < s2) red[tid] += red[tid + s2];
      __syncthreads();
    }
    float inv = 1.f / red[0];
    __syncthreads();
    sc[tid] = e * inv;
    __syncthreads();
    float acc = 0.f;
#pragma unroll 8
    for (int t = 0; t < T_; ++t) {
      acc += sc[t] * b2f(hs[((size_t)(t + 1) * B_ + b) * H_ + tid]);
    }
    wv_s[tid] = acc;
    __syncthreads();
  }

  // ---- phase C (k_ao): merged_state = [Wov @ w_b + bov, s_b] ----
  {
    for (int i = tid; i < E_; i += 256) {
      float acc = bov[i];
      for (int jj = 0; jj < H_; ++jj) acc += Wovt[(size_t)jj * E_ + i] * wv_s[jj];
      mst_l[i] = acc;
    }
    if (tid < F_) mst_l[E_ + tid] = s[(size_t)b * F_ + tid];
    __syncthreads();
  }

  // ---- phase D (k_vqc): 10-qubit statevector sim ----
  {
    if (tid < 40) ang[tid] = tanhf(mst_l[tid]) * PI_F;
    uwl[tid] = uwg[tid];
    if (tid < 64) uwl[256 + tid] = uwg[256 + tid];
#pragma unroll
    for (int k = 0; k < 4; ++k) psi[tid + k * 256] = make_float2(0.03125f, 0.f);
    __syncthreads();
    for (int l = 0; l < 4; ++l) {
      for (int q = 0; q < 10; ++q) {
        int lq = l * 10 + q;
        float a = ang[lq];
        float ca = __cosf(0.5f * a), sa = __sinf(0.5f * a);
        float cs = ca * sa;
        float2 m00 = make_float2(ca * ca, sa * sa);
        float2 m01 = make_float2(-cs, -cs);
        float2 m10 = make_float2(cs, -cs);
        float2 m11 = make_float2(ca * ca, -sa * sa);
        const float* uwp = &uwl[lq * 8];
        float2 a00 = make_float2(uwp[0], uwp[1]), a01 = make_float2(uwp[2], uwp[3]);
        float2 a10 = make_float2(uwp[4], uwp[5]), a11 = make_float2(uwp[6], uwp[7]);
        float2 u00 = cadd(cmul(a00, m00), cmul(a01, m10));
        float2 u01 = cadd(cmul(a00, m01), cmul(a01, m11));
        float2 u10 = cadd(cmul(a10, m00), cmul(a11, m10));
        float2 u11 = cadd(cmul(a10, m01), cmul(a11, m11));
        int bp = 9 - q;
        __syncthreads();
#pragma unroll
        for (int k = 0; k < 2; ++k) {
          int p = tid + k * 256;
          int i0 = ((p >> bp) << (bp + 1)) | (p & ((1 << bp) - 1));
          int i1 = i0 | (1 << bp);
          float2 A0 = psi[i0], A1 = psi[i1];
          psi[i0] = cadd(cmul(u00, A0), cmul(u01, A1));
          psi[i1] = cadd(cmul(u10, A0), cmul(u11, A1));
        }
      }
      for (int q = 0; q < 9; ++q) {  // CNOT(q, q+1): adjacent bits
        int lo = 8 - q;
        __syncthreads();
        int p = tid;
        int i0 = ((p >> lo) << (lo + 2)) | (2 << lo) | (p & ((1 << lo) - 1));
        int i1 = i0 | (1 << lo);
        float2 tmp = psi[i0]; psi[i0] = psi[i1]; psi[i1] = tmp;
      }
      __syncthreads();  // CNOT(9, 0): ctrl bit0, tgt bit9
      {
        int i0 = (tid << 1) | 1;
        int i1 = i0 | 512;
        float2 tmp = psi[i0]; psi[i0] = psi[i1]; psi[i1] = tmp;
      }
    }
    __syncthreads();
    float acc[10];
#pragma unroll
    for (int q = 0; q < 10; ++q) acc[q] = 0.f;
#pragma unroll
    for (int k = 0; k < 4; ++k) {
      int idx = tid + k * 256;
      float2 A = psi[idx];
      float pr = A.x * A.x + A.y * A.y;
#pragma unroll
      for (int q = 0; q < 10; ++q) acc[q] += ((idx >> (9 - q)) & 1) ? -pr : pr;
    }
#pragma unroll
    for (int q = 0; q < 10; ++q) {
      float vq = acc[q];
#pragma unroll
      for (int off = 32; off > 0; off >>= 1) vq += __shfl_xor(vq, off, 64);
      if (lane == 0) part[wid][q] = vq;
    }
    __syncthreads();
    if (tid < 10) qf_s[tid] = part[0][tid] + part[1][tid] + part[2][tid] + part[3][tid];
  }

  // ---- phase E (k_mlp): x1 = relu([mst,qf] @ W1^T + b1); out = x1 @ W2^T + b2
  {
    for (int i = tid; i < DM; i += 256) mg[i] = mst_l[i];
    if (tid < 10) mg[DM + tid] = qf_s[tid];   // same threads wrote qf_s
    __syncthreads();
#pragma unroll
    for (int hh = 0; hh < 2; ++hh) {
      int nn = tid + hh * 256;
      float acc = b1[nn];
#pragma unroll 4
      for (int k = 0; k < KMLP; ++k) acc += W1t[(size_t)k * NL1 + nn] * mg[k];
      x1[nn] = fmaxf(acc, 0.f);
    }
    __syncthreads();
    int a = tid >> 5, l32 = tid & 31;
    float p = 0.f;
    for (int k = l32; k < NL1; k += 32) p += x1[k] * W2[(size_t)a * NL1 + k];
    red[tid] = p;
    __syncthreads();
    if (tid < 8) {
      float acc = b2[tid];
#pragma unroll
      for (int i = 0; i < 32; ++i) acc += red[tid * 32 + i];
      out[(size_t)b * NACT + tid] = acc;
    }
  }
}

// ---------------------------------------------------------------------------
extern "C" void kernel_launch(void* const* d_in, const int* in_sizes, int n_in,
                              void* d_out, int out_size, void* d_ws, size_t ws_size,
                              hipStream_t stream) {
  const float* s      = (const float*)d_in[0];
  const float* lstm_s = (const float*)d_in[1];
  const float* W_ih   = (const float*)d_in[2];
  const float* W_hh   = (const float*)d_in[3];
  const float* b_ih   = (const float*)d_in[4];
  const float* b_hh   = (const float*)d_in[5];
  const float* projW  = (const float*)d_in[6];
  const float* projb  = (const float*)d_in[7];
  const float* ipw    = (const float*)d_in[8];
  const float* ipb    = (const float*)d_in[9];
  const float* opw    = (const float*)d_in[10];
  const float* opb    = (const float*)d_in[11];
  const float* qw     = (const float*)d_in[12];
  const float* W1     = (const float*)d_in[13];
  const float* b1     = (const float*)d_in[14];
  const float* W2     = (const float*)d_in[15];
  const float* b2     = (const float*)d_in[16];
  float* out = (float*)d_out;

  char* wsb = (char*)d_ws;
  size_t off = 0;
  auto alloc = [&](size_t bytes) -> void* {
    void* p = wsb + off;
    off = (off + bytes + 255) & ~(size_t)255;
    return p;
  };
  u16*  xbf  = (u16*)alloc((size_t)T_ * B_ * DIN * 2);
  u16*  hs   = (u16*)alloc((size_t)(T_ + 1) * B_ * H_ * 2);
  u16*  Wg   = (u16*)alloc((size_t)G4 * 384 * 2);
  float* bb  = (float*)alloc(G4 * 4);
  float* Wkp = (float*)alloc((size_t)E_ * H_ * 4);
  float* Wvp = (float*)alloc((size_t)E_ * H_ * 4);
  float* bkp = (float*)alloc(E_ * 4);
  float* bvp = (float*)alloc(E_ * 4);
  float* WuT = (float*)alloc((size_t)E_ * H_ * 4);
  float* bu  = (float*)alloc(H_ * 4);
  float* wd  = (float*)alloc(E_ * 4);
  float* ddp = (float*)alloc(256);
  float* Wovt= (float*)alloc((size_t)H_ * E_ * 4);
  float* bov = (float*)alloc(E_ * 4);
  float* uw  = (float*)alloc(40 * 8 * 4);
  float* W1t = (float*)alloc((size_t)KMLP * NL1 * 4);
  u32*  cnt  = (u32*)alloc(1024 * 4);
  (void)ws_size; (void)in_sizes; (void)n_in; (void)out_size;

  hipLaunchKernelGGL(k_prep1, dim3(9241), dim3(256), 0, stream,
                     lstm_s, W_ih, W_hh, b_ih, b_hh, ipw, ipb, projb, qw, W1,
                     xbf, hs, Wg, bb, W1t, uw, bkp, bvp, cnt);
  hipLaunchKernelGGL(k_prep2, dim3(640), dim3(256), 0, stream, ipw, projW, Wkp, Wvp);
  hipLaunchKernelGGL(k_prep3, dim3(577), dim3(256), 0, stream,
                     ipw, ipb, opw, opb, Wkp, Wvp, bkp, bvp, WuT, bu, wd, ddp, Wovt, bov);

  LstmArgs la;
  la.xbf = xbf; la.hs = hs; la.Wg = Wg; la.bb = bb; la.cnt = cnt;
  void* kargs[] = { (void*)&la };
  hipError_t ce = hipLaunchCooperativeKernel(reinterpret_cast<const void*>(&k_lstm),
                                             dim3(256), dim3(256), kargs, 0, stream);
  if (ce != hipSuccess) {
    // fallback: plain launch (256 blocks on 256 CUs co-schedule in practice)
    hipLaunchKernelGGL(k_lstm, dim3(256), dim3(256), 0, stream, la);
  }

  hipLaunchKernelGGL(k_post, dim3(512), dim3(256), 0, stream,
                     hs, s, WuT, bu, wd, ddp, Wovt, bov, uw, W1t, b1, W2, b2, out);
}

// Round 8
// 1206.252 us; speedup vs baseline: 2.4005x; 1.0733x over previous
//
#include <hip/hip_runtime.h>
#include <hip/hip_bf16.h>
#include <math.h>

typedef unsigned int u32;
typedef unsigned long long u64;
typedef unsigned short u16;
typedef __attribute__((ext_vector_type(8))) short short8;
typedef __attribute__((ext_vector_type(4))) float f32x4;
typedef __attribute__((ext_vector_type(4))) int v4i;

#define PI_F 3.14159265358979f
#define B_   512
#define T_   256
#define DIN  128
#define H_   256
#define G4   1024
#define F_   64
#define E_   320
#define DM   384
#define NL1  512
#define NACT 8
#define KMLP 394

// Raw buffer intrinsics (CK idiom) with explicit cache policy. aux=17 =
// sc0|sc1: bypass L1+L2, read/write at the device coherence point (MALL).
// The ONLY scope proven (R0-R7) for cross-block store->load visibility.
// R0's barrier (syncthreads-drain -> agent atomicAdd -> tid0 poll ->
// syncthreads) is the empirical optimum for cross-CU sync; every
// alternative tried (sentinel R1/R3/R6, SC0-only R2, flags R4, sharded R5)
// measured worse.
__device__ v4i llvm_amdgcn_raw_buffer_load_v4i32(v4i rsrc, int voffset,
                                                 int soffset, int aux)
    __asm("llvm.amdgcn.raw.buffer.load.v4i32");
__device__ float llvm_amdgcn_raw_buffer_load_f32(v4i rsrc, int voffset,
                                                 int soffset, int aux)
    __asm("llvm.amdgcn.raw.buffer.load.f32");
__device__ void llvm_amdgcn_raw_buffer_store_i32(int vdata, v4i rsrc,
                                                 int voffset, int soffset,
                                                 int aux)
    __asm("llvm.amdgcn.raw.buffer.store.i32");
__device__ void llvm_amdgcn_raw_buffer_store_f32(float vdata, v4i rsrc,
                                                 int voffset, int soffset,
                                                 int aux)
    __asm("llvm.amdgcn.raw.buffer.store.f32");

__device__ __forceinline__ v4i make_srd(const void* p) {
  v4i r;
  r.x = (int)(u32)(u64)p;
  r.y = (int)(u32)((u64)p >> 32);   // base hi, stride=0
  r.z = (int)0xFFFFFFFFu;           // num_records: bounds check disabled
  r.w = 0x00020000;                 // raw untyped dword access
  return r;
}

__device__ __forceinline__ float b2f(u16 h) {
  union { u32 u; float f; } v; v.u = ((u32)h) << 16; return v.f;
}
__device__ __forceinline__ u16 f2b(float f) {
  union { float f; u32 u; } v; v.f = f;
  u32 r = (v.u + 0x7FFFu + ((v.u >> 16) & 1u)) >> 16;
  return (u16)r;
}
__device__ __forceinline__ float sigf(float x) { return 1.0f / (1.0f + __expf(-x)); }
__device__ __forceinline__ float tanhfast(float x) { return 2.0f / (1.0f + __expf(-2.0f * x)) - 1.0f; }
__device__ __forceinline__ float2 cmul(float2 a, float2 b) {
  return make_float2(a.x * b.x - a.y * b.y, a.x * b.y + a.y * b.x);
}
__device__ __forceinline__ float2 cadd(float2 a, float2 b) {
  return make_float2(a.x + b.x, a.y + b.y);
}

// ---------------------------------------------------------------------------
// prep1: x transpose+bf16, Wg=[W_ih|W_hh] bf16, zero hs[0], W1t, bb, uw, bkp,
// bvp, zero barrier counters  (exact R0 version)
// ---------------------------------------------------------------------------
__global__ void k_prep1(const float* __restrict__ lstm_s,
                        const float* __restrict__ W_ih,
                        const float* __restrict__ W_hh,
                        const float* __restrict__ b_ih,
                        const float* __restrict__ b_hh,
                        const float* __restrict__ ipw,
                        const float* __restrict__ ipb,
                        const float* __restrict__ projb,
                        const float* __restrict__ qw,
                        const float* __restrict__ W1,
                        u16* __restrict__ xbf,
                        u16* __restrict__ hs,
                        u16* __restrict__ Wg,
                        float* __restrict__ bb,
                        float* __restrict__ W1t,
                        float* __restrict__ uw,
                        float* __restrict__ bkp,
                        float* __restrict__ bvp,
                        u32* __restrict__ cnt) {
  const int bid = blockIdx.x;
  const int tid = threadIdx.x;
  if (bid < 8192) {                       // lstm_s (B,T,128) -> xbf (T,B,128) bf16
    u32 u = (u32)bid * 256u + tid;        // < 2097152 uint4 units
    u32 c8 = u & 15u, b = (u >> 4) & 511u, t = u >> 13;
    const float* src = lstm_s + ((size_t)b * T_ + t) * DIN + c8 * 8;
    union { u16 h[8]; uint4 v; } tmp;
#pragma unroll
    for (int i = 0; i < 8; ++i) tmp.h[i] = f2b(src[i]);
    *(uint4*)(xbf + ((size_t)t * B_ + b) * DIN + c8 * 8) = tmp.v;
  } else if (bid < 8384) {                // Wg (1024 x 384) bf16
    u32 u = (u32)(bid - 8192) * 256u + tid;  // < 49152
    u32 c8 = u % 48u, r = u / 48u;
    const float* src = (c8 < 16) ? (W_ih + (size_t)r * DIN + c8 * 8)
                                 : (W_hh + (size_t)r * H_ + (c8 - 16) * 8);
    union { u16 h[8]; uint4 v; } tmp;
#pragma unroll
    for (int i = 0; i < 8; ++i) tmp.h[i] = f2b(src[i]);
    *(uint4*)(Wg + (size_t)r * 384 + c8 * 8) = tmp.v;
  } else if (bid < 8448) {                // zero hs[0]
    u32 u = (u32)(bid - 8384) * 256u + tid;  // < 16384
    ((uint4*)hs)[u] = make_uint4(0, 0, 0, 0);
  } else if (bid < 9236) {                // W1t[k][n] = W1[n][k]
    u32 u = (u32)(bid - 8448) * 256u + tid;  // < 201728
    u32 k = u / 512u, nn = u % 512u;
    W1t[u] = W1[(size_t)nn * KMLP + k];
  } else if (bid == 9236) {               // bb, cnt, uw
    for (int i = tid; i < 1024; i += 256) bb[i] = b_ih[i] + b_hh[i];
    for (int i = tid; i < 1024; i += 256) cnt[i] = 0u;
    if (tid < 40) {
      float w0 = qw[tid * 3 + 0], w1 = qw[tid * 3 + 1], w2 = qw[tid * 3 + 2];
      float c0 = cosf(0.5f * w0), s0 = sinf(0.5f * w0);
      float c1 = cosf(0.5f * w1), s1 = sinf(0.5f * w1);
      float c2 = cosf(0.5f * w2), s2 = sinf(0.5f * w2);
      float2 e0m = make_float2(c0, -s0), e0p = make_float2(c0, s0);
      float2 e2m = make_float2(c2, -s2), e2p = make_float2(c2, s2);
      // T1 = RY(w1) @ RZ(w0)
      float2 t00 = make_float2(c1 * e0m.x, c1 * e0m.y);
      float2 t01 = make_float2(-s1 * e0p.x, -s1 * e0p.y);
      float2 t10 = make_float2(s1 * e0m.x, s1 * e0m.y);
      float2 t11 = make_float2(c1 * e0p.x, c1 * e0p.y);
      // U = RZ(w2) @ T1
      float2 u00 = cmul(e2m, t00), u01 = cmul(e2m, t01);
      float2 u10 = cmul(e2p, t10), u11 = cmul(e2p, t11);
      float* o = uw + tid * 8;
      o[0] = u00.x; o[1] = u00.y; o[2] = u01.x; o[3] = u01.y;
      o[4] = u10.x; o[5] = u10.y; o[6] = u11.x; o[7] = u11.y;
    }
  } else if (bid <= 9238) {               // bkp = Wk @ proj_b + bk
    int o = (bid - 9237) * 256 + tid;
    if (o < E_) {
      float acc = ipb[E_ + o];
      for (int e = 0; e < E_; ++e) acc += ipw[(size_t)(E_ + o) * E_ + e] * projb[e];
      bkp[o] = acc;
    }
  } else {                                // bvp = Wv @ proj_b + bv
    int o = (bid - 9239) * 256 + tid;
    if (o < E_) {
      float acc = ipb[2 * E_ + o];
      for (int e = 0; e < E_; ++e) acc += ipw[(size_t)(2 * E_ + o) * E_ + e] * projb[e];
      bvp[o] = acc;
    }
  }
}

// ---------------------------------------------------------------------------
// k_lstm, extended grid: blocks 0..255 = EXACT R0 LSTM body (proven
// 3.40us/step optimum); blocks 256..511 = prep2+prep3 work, co-resident on
// the same CUs (2 blocks/CU) and hidden inside the LSTM's ~75% idle VALU
// time. Prep blocks: Wkp/Wvp (fused, shared projW reads) -> one-shot
// R0-style counter barrier at cnt[768] (aux17 stores drained by
// __syncthreads' vmcnt(0), then agent atomicAdd + poll — the proven
// visibility chain) -> WuT/Wovt/bu/wd/ddp/bov.
// ---------------------------------------------------------------------------
struct LstmArgs {
  const u16* xbf; u16* hs; const u16* Wg; const float* bb; u32* cnt;
  const float* ipw; const float* ipb; const float* projW;
  const float* opw; const float* opb;
  const float* bkp; const float* bvp;
  float* Wkp; float* Wvp;
  float* WuT; float* bu; float* wd; float* ddp; float* Wovt; float* bov;
};

__launch_bounds__(256, 1)
__global__ void k_lstm(LstmArgs A) {
  const int tid = threadIdx.x;
  __shared__ __align__(16) u16 Wl[32 * 392];  // 32 gate rows x 384 K, pad to 392

  if (blockIdx.x >= 256) {
    // ================= prep blocks (hidden under the LSTM) =================
    const int p = blockIdx.x - 256;           // 0..255
    const v4i kp_srd = make_srd(A.Wkp);
    const v4i vp_srd = make_srd(A.Wvp);
    // --- prep2: Wkp[o][tid], Wvp[o][tid] (fused; shared projW column) ---
    for (int o = p; o < E_; o += 256) {
      const float* rk = A.ipw + (size_t)(E_ + o) * E_;
      const float* rv = A.ipw + (size_t)(2 * E_ + o) * E_;
      float ak = 0.f, av = 0.f;
#pragma unroll 4
      for (int e = 0; e < E_; ++e) {
        float pw = A.projW[(size_t)e * H_ + tid];
        ak += rk[e] * pw;
        av += rv[e] * pw;
      }
      llvm_amdgcn_raw_buffer_store_f32(ak, kp_srd, (o * H_ + tid) * 4, 0, 17);
      llvm_amdgcn_raw_buffer_store_f32(av, vp_srd, (o * H_ + tid) * 4, 0, 17);
    }
    // --- one-shot barrier among the 256 prep blocks (R0 chain) ---
    __syncthreads();   // implicit vmcnt(0): aux17 stores at MALL
    if (tid == 0) {
      u32* pc = A.cnt + 768;
      __hip_atomic_fetch_add(pc, 1u, __ATOMIC_RELAXED, __HIP_MEMORY_SCOPE_AGENT);
      int guard = 0;
      while (__hip_atomic_load(pc, __ATOMIC_RELAXED, __HIP_MEMORY_SCOPE_AGENT) < 256u) {
        __builtin_amdgcn_s_sleep(1);
        if (++guard > (1 << 24)) break;
      }
    }
    __syncthreads();
    // --- prep3a: WuT[e][tid] = sum_o Wkp[o][tid] * Wq[o][e] ---
    for (int e = p; e < E_; e += 256) {
      float acc = 0.f;
#pragma unroll 4
      for (int o = 0; o < E_; ++o) {
        float kv = llvm_amdgcn_raw_buffer_load_f32(kp_srd, (o * H_ + tid) * 4, 0, 17);
        acc += kv * A.ipw[(size_t)o * E_ + e];
      }
      A.WuT[(size_t)e * H_ + tid] = acc;    // plain store: read by next kernel
    }
    // --- prep3b: Wovt[jj][i] = sum_o opw[i][o] * Wvp[o][jj]  (jj = p) ---
    {
      const int jj = p;
      for (int i = tid; i < E_; i += 256) {
        const float* wo = A.opw + (size_t)i * E_;
        float acc = 0.f;
#pragma unroll 4
        for (int o = 0; o < E_; ++o) {
          float vv = llvm_amdgcn_raw_buffer_load_f32(vp_srd, (o * H_ + jj) * 4, 0, 17);
          acc += wo[o] * vv;
        }
        A.Wovt[(size_t)jj * E_ + i] = acc;
      }
    }
    // --- prep3c (block 0 only): bu, wd, ddp, bov ---
    if (p == 0) {
      {
        float acc = 0.f;
#pragma unroll 4
        for (int o = 0; o < E_; ++o) {
          float kv = llvm_amdgcn_raw_buffer_load_f32(kp_srd, (o * H_ + tid) * 4, 0, 17);
          acc += kv * A.ipb[o];
        }
        A.bu[tid] = acc;
      }
      for (int idx = tid; idx < E_; idx += 256) {
        float a1 = 0.f, a2 = A.opb[idx];
#pragma unroll 4
        for (int o = 0; o < E_; ++o) {
          a1 += A.ipw[(size_t)o * E_ + idx] * A.bkp[o];
          a2 += A.opw[(size_t)idx * E_ + o] * A.bvp[o];
        }
        A.wd[idx] = a1; A.bov[idx] = a2;
      }
      if (tid == 0) {
        float acc = 0.f;
        for (int o = 0; o < E_; ++o) acc += A.ipb[o] * A.bkp[o];
        A.ddp[0] = acc;
      }
    }
    return;
  }

  // ======================= LSTM blocks (exact R0 body) =====================
  const int g   = blockIdx.x & 7;
  const int n   = blockIdx.x >> 3;            // 0..31
  const int wid = tid >> 6, lane = tid & 63;

  for (int idx = tid; idx < 32 * 48; idx += 256) {
    int ln = idx / 48, c8 = idx % 48;
    int gr = (ln >> 3) * 256 + n * 8 + (ln & 7);
    *(uint4*)&Wl[ln * 392 + c8 * 8] = *(const uint4*)&A.Wg[(size_t)gr * 384 + c8 * 8];
  }
  const int j  = lane & 7;
  const int gc = n * 8 + j;
  const float bbi = A.bb[gc], bbf2 = A.bb[256 + gc];
  const float bbg = A.bb[512 + gc], bbo = A.bb[768 + gc];

  const int quad = lane >> 4;
  const int mrow = lane & 15;
  const int brow = g * 64 + wid * 16 + mrow;
  const int erow0 = g * 64 + wid * 16 + quad * 4;
  const bool hi = (lane & 8) != 0;
  float crs[4] = {0.f, 0.f, 0.f, 0.f};
  u32* mycnt = A.cnt + g * 64;
  u32 target = 0;

  const v4i hs_srd = make_srd(A.hs);
  const int hvoff = (brow * H_ + quad * 8) * 2;   // per-lane byte offset in a step-block

  // prologue: x[0]
  uint4 xc0, xc1, xc2, xc3, xn0, xn1, xn2, xn3;
  {
    const u16* xb = A.xbf + ((size_t)0 * B_ + brow) * DIN + quad * 8;
    xc0 = *(const uint4*)(xb + 0);
    xc1 = *(const uint4*)(xb + 32);
    xc2 = *(const uint4*)(xb + 64);
    xc3 = *(const uint4*)(xb + 96);
  }
  __syncthreads();  // Wl staged

  for (int t = 0; t < T_; ++t) {
    // h_t loads: coherent (sc0|sc1) pipelined buffer loads
    const int hsoff = t * (B_ * H_ * 2);
    uint4 h0 = __builtin_bit_cast(uint4, llvm_amdgcn_raw_buffer_load_v4i32(hs_srd, hvoff +   0, hsoff, 17));
    uint4 h1 = __builtin_bit_cast(uint4, llvm_amdgcn_raw_buffer_load_v4i32(hs_srd, hvoff +  64, hsoff, 17));
    uint4 h2 = __builtin_bit_cast(uint4, llvm_amdgcn_raw_buffer_load_v4i32(hs_srd, hvoff + 128, hsoff, 17));
    uint4 h3 = __builtin_bit_cast(uint4, llvm_amdgcn_raw_buffer_load_v4i32(hs_srd, hvoff + 192, hsoff, 17));
    uint4 h4 = __builtin_bit_cast(uint4, llvm_amdgcn_raw_buffer_load_v4i32(hs_srd, hvoff + 256, hsoff, 17));
    uint4 h5 = __builtin_bit_cast(uint4, llvm_amdgcn_raw_buffer_load_v4i32(hs_srd, hvoff + 320, hsoff, 17));
    uint4 h6 = __builtin_bit_cast(uint4, llvm_amdgcn_raw_buffer_load_v4i32(hs_srd, hvoff + 384, hsoff, 17));
    uint4 h7 = __builtin_bit_cast(uint4, llvm_amdgcn_raw_buffer_load_v4i32(hs_srd, hvoff + 448, hsoff, 17));
    // x[t+1] prefetch (plain cached loads; drained by the barrier's vmcnt(0))
    {
      const int tn = (t + 1 < T_) ? (t + 1) : t;
      const u16* xb = A.xbf + ((size_t)tn * B_ + brow) * DIN + quad * 8;
      xn0 = *(const uint4*)(xb + 0);
      xn1 = *(const uint4*)(xb + 32);
      xn2 = *(const uint4*)(xb + 64);
      xn3 = *(const uint4*)(xb + 96);
    }

    f32x4 acc0 = {0.f, 0.f, 0.f, 0.f}, acc1 = {0.f, 0.f, 0.f, 0.f};
#define MMSTEP(AV, KOFF)                                                          \
    {                                                                             \
      short8 av  = __builtin_bit_cast(short8, AV);                                \
      short8 bv0 = __builtin_bit_cast(short8,                                     \
          *(const uint4*)&Wl[mrow * 392 + (KOFF) + quad * 8]);                    \
      short8 bv1 = __builtin_bit_cast(short8,                                     \
          *(const uint4*)&Wl[(16 + mrow) * 392 + (KOFF) + quad * 8]);             \
      acc0 = __builtin_amdgcn_mfma_f32_16x16x32_bf16(av, bv0, acc0, 0, 0, 0);     \
      acc1 = __builtin_amdgcn_mfma_f32_16x16x32_bf16(av, bv1, acc1, 0, 0, 0);     \
    }
    MMSTEP(xc0, 0)   MMSTEP(xc1, 32)  MMSTEP(xc2, 64)  MMSTEP(xc3, 96)
    MMSTEP(h0, 128)  MMSTEP(h1, 160)  MMSTEP(h2, 192)  MMSTEP(h3, 224)
    MMSTEP(h4, 256)  MMSTEP(h5, 288)  MMSTEP(h6, 320)  MMSTEP(h7, 352)
#undef MMSTEP

    // epilogue: lanes bit3=0 hold i (tile0) & g (tile1); bit3=1 hold f & o
    const int hsoff_o = (t + 1) * (B_ * H_ * 2);
#pragma unroll
    for (int r = 0; r < 4; ++r) {
      float x0 = acc0[r], x1v = acc1[r];
      float y0 = __shfl_xor(x0, 8, 64);
      float y1 = __shfl_xor(x1v, 8, 64);
      float iv = (hi ? y0 : x0) + bbi;
      float fv = (hi ? x0 : y0) + bbf2;
      float gv = (hi ? y1 : x1v) + bbg;
      float ov = (hi ? x1v : y1) + bbo;
      float cc = sigf(fv) * crs[r] + sigf(iv) * tanhfast(gv);
      crs[r] = cc;
      float hh = sigf(ov) * tanhfast(cc);
      float hh2 = __shfl_xor(hh, 1, 64);      // partner column's h
      if (!hi && ((j & 1) == 0)) {
        u32 pk = (u32)f2b(hh) | ((u32)f2b(hh2) << 16);
        llvm_amdgcn_raw_buffer_store_i32((int)pk, hs_srd,
                                         ((erow0 + r) * H_ + gc) * 2, hsoff_o, 17);
      }
    }
    // ---- group barrier (release h_t, acquire peers' h_t) ----
    target += 32;
    if (t != T_ - 1) {
      __syncthreads();   // implicit vmcnt(0): h stores at MALL, x prefetch done
      if (tid == 0) {
        __hip_atomic_fetch_add(mycnt, 1u, __ATOMIC_RELAXED, __HIP_MEMORY_SCOPE_AGENT);
        int guard = 0;
        while (__hip_atomic_load(mycnt, __ATOMIC_RELAXED, __HIP_MEMORY_SCOPE_AGENT) < target) {
          __builtin_amdgcn_s_sleep(1);
          if (++guard > (1 << 24)) break;
        }
      }
      __syncthreads();
      xc0 = xn0; xc1 = xn1; xc2 = xn2; xc3 = xn3;
    }
  }
}

// ---------------------------------------------------------------------------
// k_post: fused tail. All matvec phases rewritten with 2 independent
// accumulator streams + unroll 8 (16 loads in flight) — R7 diagnosis:
// these loops were LATENCY-bound (~8B/cy/CU effective) with default codegen.
// ---------------------------------------------------------------------------
__global__ void k_post(const u16* __restrict__ hs, const float* __restrict__ s,
                       const float* __restrict__ WuT, const float* __restrict__ bu,
                       const float* __restrict__ wd, const float* __restrict__ ddp,
                       const float* __restrict__ Wovt, const float* __restrict__ bov,
                       const float* __restrict__ uwg,
                       const float* __restrict__ W1t, const float* __restrict__ b1,
                       const float* __restrict__ W2, const float* __restrict__ b2,
                       float* __restrict__ out) {
  int b = blockIdx.x, tid = threadIdx.x;
  int wid = tid >> 6, lane = tid & 63;
  __shared__ float z[E_];
  __shared__ float red[256];
  __shared__ float ul_s[H_];
  __shared__ float sc[T_];
  __shared__ float wv_s[H_];
  __shared__ float mst_l[DM];
  __shared__ float dvec_s;
  __shared__ float2 psi[1024];
  __shared__ float ang[40];
  __shared__ float uwl[320];
  __shared__ float part[4][10];
  __shared__ float qf_s[10];
  __shared__ float mg[KMLP];
  __shared__ float x1[NL1];

  // ---- phase A (k_u): u_b and d_b ----
  z[tid] = b2f(hs[((size_t)T_ * B_ + b) * H_ + tid]);
  if (tid < F_) z[H_ + tid] = s[(size_t)b * F_ + tid];
  __syncthreads();
  {
    float a0 = bu[tid], a1 = 0.f;
#pragma unroll 8
    for (int e = 0; e < 160; ++e) {
      a0 += WuT[(size_t)e * H_ + tid] * z[e];
      a1 += WuT[(size_t)(e + 160) * H_ + tid] * z[e + 160];
    }
    ul_s[tid] = a0 + a1;
    float p = 0.f;
    for (int e = tid; e < E_; e += 256) p += wd[e] * z[e];
    red[tid] = p;
    __syncthreads();
    for (int s2 = 128; s2 > 0; s2 >>= 1) {
      if (tid < s2) red[tid] += red[tid + s2];
      __syncthreads();
    }
    if (tid == 0) dvec_s = red[0] + ddp[0];
    __syncthreads();
  }

  // ---- phase B (k_aw): scores -> softmax -> wv ----
  {
    const float db = dvec_s;
    const float scale = 0.055901699437494745f;  // 1/sqrt(320)
    float4 ul = make_float4(ul_s[lane * 4], ul_s[lane * 4 + 1],
                            ul_s[lane * 4 + 2], ul_s[lane * 4 + 3]);
    for (int tt = 0; tt < 64; ++tt) {
      int t = wid * 64 + tt;
      u32 rw0 = ((const u32*)(hs + ((size_t)(t + 1) * B_ + b) * H_))[lane * 2];
      u32 rw1 = ((const u32*)(hs + ((size_t)(t + 1) * B_ + b) * H_))[lane * 2 + 1];
      union { u32 uu; float f; } f0, f1, f2, f3;
      f0.uu = rw0 << 16; f1.uu = rw0 & 0xFFFF0000u;
      f2.uu = rw1 << 16; f3.uu = rw1 & 0xFFFF0000u;
      float p = f0.f * ul.x + f1.f * ul.y + f2.f * ul.z + f3.f * ul.w;
#pragma unroll
      for (int off = 32; off > 0; off >>= 1) p += __shfl_xor(p, off, 64);
      if (lane == 0) sc[t] = (p + db) * scale;
    }
    __syncthreads();
    float v = sc[tid];
    red[tid] = v;
    __syncthreads();
    for (int s2 = 128; s2 > 0; s2 >>= 1) {
      if (tid < s2) red[tid] = fmaxf(red[tid], red[tid + s2]);
      __syncthreads();
    }
    float m = red[0];
    __syncthreads();
    float e = __expf(v - m);
    red[tid] = e;
    __syncthreads();
    for (int s2 = 128; s2 > 0; s2 >>= 1) {
      if (tid < s2) red[tid] += red[tid + s2];
      __syncthreads();
    }
    float inv = 1.f / red[0];
    __syncthreads();
    sc[tid] = e * inv;
    __syncthreads();
    float a0 = 0.f, a1 = 0.f;
#pragma unroll 8
    for (int t = 0; t < 128; ++t) {
      a0 += sc[t]       * b2f(hs[((size_t)(t + 1) * B_ + b) * H_ + tid]);
      a1 += sc[t + 128] * b2f(hs[((size_t)(t + 129) * B_ + b) * H_ + tid]);
    }
    wv_s[tid] = a0 + a1;
    __syncthreads();
  }

  // ---- phase C (k_ao): merged_state = [Wov @ w_b + bov, s_b] ----
  {
    for (int i = tid; i < E_; i += 256) {
      float a0 = bov[i], a1 = 0.f;
#pragma unroll 8
      for (int jj = 0; jj < 128; ++jj) {
        a0 += Wovt[(size_t)jj * E_ + i] * wv_s[jj];
        a1 += Wovt[(size_t)(jj + 128) * E_ + i] * wv_s[jj + 128];
      }
      mst_l[i] = a0 + a1;
    }
    if (tid < F_) mst_l[E_ + tid] = s[(size_t)b * F_ + tid];
    __syncthreads();
  }

  // ---- phase D (k_vqc): 10-qubit statevector sim ----
  {
    if (tid < 40) ang[tid] = tanhf(mst_l[tid]) * PI_F;
    uwl[tid] = uwg[tid];
    if (tid < 64) uwl[256 + tid] = uwg[256 + tid];
#pragma unroll
    for (int k = 0; k < 4; ++k) psi[tid + k * 256] = make_float2(0.03125f, 0.f);
    __syncthreads();
    for (int l = 0; l < 4; ++l) {
      for (int q = 0; q < 10; ++q) {
        int lq = l * 10 + q;
        float a = ang[lq];
        float ca = __cosf(0.5f * a), sa = __sinf(0.5f * a);
        float cs = ca * sa;
        float2 m00 = make_float2(ca * ca, sa * sa);
        float2 m01 = make_float2(-cs, -cs);
        float2 m10 = make_float2(cs, -cs);
        float2 m11 = make_float2(ca * ca, -sa * sa);
        const float* uwp = &uwl[lq * 8];
        float2 a00 = make_float2(uwp[0], uwp[1]), a01 = make_float2(uwp[2], uwp[3]);
        float2 a10 = make_float2(uwp[4], uwp[5]), a11 = make_float2(uwp[6], uwp[7]);
        float2 u00 = cadd(cmul(a00, m00), cmul(a01, m10));
        float2 u01 = cadd(cmul(a00, m01), cmul(a01, m11));
        float2 u10 = cadd(cmul(a10, m00), cmul(a11, m10));
        float2 u11 = cadd(cmul(a10, m01), cmul(a11, m11));
        int bp = 9 - q;
        __syncthreads();
#pragma unroll
        for (int k = 0; k < 2; ++k) {
          int p = tid + k * 256;
          int i0 = ((p >> bp) << (bp + 1)) | (p & ((1 << bp) - 1));
          int i1 = i0 | (1 << bp);
          float2 A0 = psi[i0], A1 = psi[i1];
          psi[i0] = cadd(cmul(u00, A0), cmul(u01, A1));
          psi[i1] = cadd(cmul(u10, A0), cmul(u11, A1));
        }
      }
      for (int q = 0; q < 9; ++q) {  // CNOT(q, q+1): adjacent bits
        int lo = 8 - q;
        __syncthreads();
        int p = tid;
        int i0 = ((p >> lo) << (lo + 2)) | (2 << lo) | (p & ((1 << lo) - 1));
        int i1 = i0 | (1 << lo);
        float2 tmp = psi[i0]; psi[i0] = psi[i1]; psi[i1] = tmp;
      }
      __syncthreads();  // CNOT(9, 0): ctrl bit0, tgt bit9
      {
        int i0 = (tid << 1) | 1;
        int i1 = i0 | 512;
        float2 tmp = psi[i0]; psi[i0] = psi[i1]; psi[i1] = tmp;
      }
    }
    __syncthreads();
    float acc[10];
#pragma unroll
    for (int q = 0; q < 10; ++q) acc[q] = 0.f;
#pragma unroll
    for (int k = 0; k < 4; ++k) {
      int idx = tid + k * 256;
      float2 A = psi[idx];
      float pr = A.x * A.x + A.y * A.y;
#pragma unroll
      for (int q = 0; q < 10; ++q) acc[q] += ((idx >> (9 - q)) & 1) ? -pr : pr;
    }
#pragma unroll
    for (int q = 0; q < 10; ++q) {
      float vq = acc[q];
#pragma unroll
      for (int off = 32; off > 0; off >>= 1) vq += __shfl_xor(vq, off, 64);
      if (lane == 0) part[wid][q] = vq;
    }
    __syncthreads();
    if (tid < 10) qf_s[tid] = part[0][tid] + part[1][tid] + part[2][tid] + part[3][tid];
  }

  // ---- phase E (k_mlp): x1 = relu([mst,qf] @ W1^T + b1); out = x1 @ W2^T + b2
  {
    for (int i = tid; i < DM; i += 256) mg[i] = mst_l[i];
    if (tid < 10) mg[DM + tid] = qf_s[tid];
    __syncthreads();
    float a0 = b1[tid], a1 = b1[tid + 256];
#pragma unroll 8
    for (int k = 0; k < KMLP; ++k) {
      float m = mg[k];
      a0 += W1t[(size_t)k * NL1 + tid] * m;
      a1 += W1t[(size_t)k * NL1 + tid + 256] * m;
    }
    x1[tid] = fmaxf(a0, 0.f);
    x1[tid + 256] = fmaxf(a1, 0.f);
    __syncthreads();
    int a = tid >> 5, l32 = tid & 31;
    float p = 0.f;
    for (int k = l32; k < NL1; k += 32) p += x1[k] * W2[(size_t)a * NL1 + k];
    red[tid] = p;
    __syncthreads();
    if (tid < 8) {
      float acc = b2[tid];
#pragma unroll
      for (int i = 0; i < 32; ++i) acc += red[tid * 32 + i];
      out[(size_t)b * NACT + tid] = acc;
    }
  }
}

// ---------------------------------------------------------------------------
extern "C" void kernel_launch(void* const* d_in, const int* in_sizes, int n_in,
                              void* d_out, int out_size, void* d_ws, size_t ws_size,
                              hipStream_t stream) {
  const float* s      = (const float*)d_in[0];
  const float* lstm_s = (const float*)d_in[1];
  const float* W_ih   = (const float*)d_in[2];
  const float* W_hh   = (const float*)d_in[3];
  const float* b_ih   = (const float*)d_in[4];
  const float* b_hh   = (const float*)d_in[5];
  const float* projW  = (const float*)d_in[6];
  const float* projb  = (const float*)d_in[7];
  const float* ipw    = (const float*)d_in[8];
  const float* ipb    = (const float*)d_in[9];
  const float* opw    = (const float*)d_in[10];
  const float* opb    = (const float*)d_in[11];
  const float* qw     = (const float*)d_in[12];
  const float* W1     = (const float*)d_in[13];
  const float* b1     = (const float*)d_in[14];
  const float* W2     = (const float*)d_in[15];
  const float* b2     = (const float*)d_in[16];
  float* out = (float*)d_out;

  char* wsb = (char*)d_ws;
  size_t off = 0;
  auto alloc = [&](size_t bytes) -> void* {
    void* p = wsb + off;
    off = (off + bytes + 255) & ~(size_t)255;
    return p;
  };
  u16*  xbf  = (u16*)alloc((size_t)T_ * B_ * DIN * 2);
  u16*  hs   = (u16*)alloc((size_t)(T_ + 1) * B_ * H_ * 2);
  u16*  Wg   = (u16*)alloc((size_t)G4 * 384 * 2);
  float* bb  = (float*)alloc(G4 * 4);
  float* Wkp = (float*)alloc((size_t)E_ * H_ * 4);
  float* Wvp = (float*)alloc((size_t)E_ * H_ * 4);
  float* bkp = (float*)alloc(E_ * 4);
  float* bvp = (float*)alloc(E_ * 4);
  float* WuT = (float*)alloc((size_t)E_ * H_ * 4);
  float* bu  = (float*)alloc(H_ * 4);
  float* wd  = (float*)alloc(E_ * 4);
  float* ddp = (float*)alloc(256);
  float* Wovt= (float*)alloc((size_t)H_ * E_ * 4);
  float* bov = (float*)alloc(E_ * 4);
  float* uw  = (float*)alloc(40 * 8 * 4);
  float* W1t = (float*)alloc((size_t)KMLP * NL1 * 4);
  u32*  cnt  = (u32*)alloc(1024 * 4);
  (void)ws_size; (void)in_sizes; (void)n_in; (void)out_size;

  hipLaunchKernelGGL(k_prep1, dim3(9241), dim3(256), 0, stream,
                     lstm_s, W_ih, W_hh, b_ih, b_hh, ipw, ipb, projb, qw, W1,
                     xbf, hs, Wg, bb, W1t, uw, bkp, bvp, cnt);

  LstmArgs la;
  la.xbf = xbf; la.hs = hs; la.Wg = Wg; la.bb = bb; la.cnt = cnt;
  la.ipw = ipw; la.ipb = ipb; la.projW = projW; la.opw = opw; la.opb = opb;
  la.bkp = bkp; la.bvp = bvp; la.Wkp = Wkp; la.Wvp = Wvp;
  la.WuT = WuT; la.bu = bu; la.wd = wd; la.ddp = ddp; la.Wovt = Wovt; la.bov = bov;
  void* kargs[] = { (void*)&la };
  hipError_t ce = hipLaunchCooperativeKernel(reinterpret_cast<const void*>(&k_lstm),
                                             dim3(512), dim3(256), kargs, 0, stream);
  if (ce != hipSuccess) {
    // fallback: plain launch (512 blocks at 2/CU co-schedule in practice)
    hipLaunchKernelGGL(k_lstm, dim3(512), dim3(256), 0, stream, la);
  }

  hipLaunchKernelGGL(k_post, dim3(512), dim3(256), 0, stream,
                     hs, s, WuT, bu, wd, ddp, Wovt, bov, uw, W1t, b1, W2, b2, out);
}

// Round 9
// 1183.641 us; speedup vs baseline: 2.4464x; 1.0191x over previous
//
#include <hip/hip_runtime.h>
#include <hip/hip_bf16.h>
#include <math.h>

typedef unsigned int u32;
typedef unsigned long long u64;
typedef unsigned short u16;
typedef __attribute__((ext_vector_type(8))) short short8;
typedef __attribute__((ext_vector_type(4))) float f32x4;
typedef __attribute__((ext_vector_type(4))) int v4i;

#define PI_F 3.14159265358979f
#define B_   512
#define T_   256
#define DIN  128
#define H_   256
#define G4   1024
#define F_   64
#define E_   320
#define DM   384
#define NL1  512
#define NACT 8
#define KMLP 394

// Raw buffer intrinsics (CK idiom) with explicit cache policy. aux=17 =
// sc0|sc1: bypass L1+L2, read/write at the device coherence point (MALL).
// The ONLY scope proven (R0-R8) for cross-block store->load visibility.
// R0's barrier (syncthreads-drain -> agent atomicAdd -> tid0 poll ->
// syncthreads) is the empirical optimum for cross-CU sync; every
// alternative tried (sentinel R1/R3/R6, SC0-only R2, flags R4, sharded R5)
// measured worse.
__device__ v4i llvm_amdgcn_raw_buffer_load_v4i32(v4i rsrc, int voffset,
                                                 int soffset, int aux)
    __asm("llvm.amdgcn.raw.buffer.load.v4i32");
__device__ float llvm_amdgcn_raw_buffer_load_f32(v4i rsrc, int voffset,
                                                 int soffset, int aux)
    __asm("llvm.amdgcn.raw.buffer.load.f32");
__device__ void llvm_amdgcn_raw_buffer_store_i32(int vdata, v4i rsrc,
                                                 int voffset, int soffset,
                                                 int aux)
    __asm("llvm.amdgcn.raw.buffer.store.i32");
__device__ void llvm_amdgcn_raw_buffer_store_f32(float vdata, v4i rsrc,
                                                 int voffset, int soffset,
                                                 int aux)
    __asm("llvm.amdgcn.raw.buffer.store.f32");

__device__ __forceinline__ v4i make_srd(const void* p) {
  v4i r;
  r.x = (int)(u32)(u64)p;
  r.y = (int)(u32)((u64)p >> 32);   // base hi, stride=0
  r.z = (int)0xFFFFFFFFu;           // num_records: bounds check disabled
  r.w = 0x00020000;                 // raw untyped dword access
  return r;
}

__device__ __forceinline__ float b2f(u16 h) {
  union { u32 u; float f; } v; v.u = ((u32)h) << 16; return v.f;
}
__device__ __forceinline__ u16 f2b(float f) {
  union { float f; u32 u; } v; v.f = f;
  u32 r = (v.u + 0x7FFFu + ((v.u >> 16) & 1u)) >> 16;
  return (u16)r;
}
__device__ __forceinline__ float sigf(float x) { return 1.0f / (1.0f + __expf(-x)); }
__device__ __forceinline__ float tanhfast(float x) { return 2.0f / (1.0f + __expf(-2.0f * x)) - 1.0f; }
__device__ __forceinline__ float2 cmul(float2 a, float2 b) {
  return make_float2(a.x * b.x - a.y * b.y, a.x * b.y + a.y * b.x);
}
__device__ __forceinline__ float2 cadd(float2 a, float2 b) {
  return make_float2(a.x + b.x, a.y + b.y);
}

// ---------------------------------------------------------------------------
// prep1: x transpose+bf16, Wg=[W_ih|W_hh] bf16, zero hs[0], W1t, bb, uw, bkp,
// bvp, zero barrier counters  (exact R0 version)
// ---------------------------------------------------------------------------
__global__ void k_prep1(const float* __restrict__ lstm_s,
                        const float* __restrict__ W_ih,
                        const float* __restrict__ W_hh,
                        const float* __restrict__ b_ih,
                        const float* __restrict__ b_hh,
                        const float* __restrict__ ipw,
                        const float* __restrict__ ipb,
                        const float* __restrict__ projb,
                        const float* __restrict__ qw,
                        const float* __restrict__ W1,
                        u16* __restrict__ xbf,
                        u16* __restrict__ hs,
                        u16* __restrict__ Wg,
                        float* __restrict__ bb,
                        float* __restrict__ W1t,
                        float* __restrict__ uw,
                        float* __restrict__ bkp,
                        float* __restrict__ bvp,
                        u32* __restrict__ cnt) {
  const int bid = blockIdx.x;
  const int tid = threadIdx.x;
  if (bid < 8192) {                       // lstm_s (B,T,128) -> xbf (T,B,128) bf16
    u32 u = (u32)bid * 256u + tid;        // < 2097152 uint4 units
    u32 c8 = u & 15u, b = (u >> 4) & 511u, t = u >> 13;
    const float* src = lstm_s + ((size_t)b * T_ + t) * DIN + c8 * 8;
    union { u16 h[8]; uint4 v; } tmp;
#pragma unroll
    for (int i = 0; i < 8; ++i) tmp.h[i] = f2b(src[i]);
    *(uint4*)(xbf + ((size_t)t * B_ + b) * DIN + c8 * 8) = tmp.v;
  } else if (bid < 8384) {                // Wg (1024 x 384) bf16
    u32 u = (u32)(bid - 8192) * 256u + tid;  // < 49152
    u32 c8 = u % 48u, r = u / 48u;
    const float* src = (c8 < 16) ? (W_ih + (size_t)r * DIN + c8 * 8)
                                 : (W_hh + (size_t)r * H_ + (c8 - 16) * 8);
    union { u16 h[8]; uint4 v; } tmp;
#pragma unroll
    for (int i = 0; i < 8; ++i) tmp.h[i] = f2b(src[i]);
    *(uint4*)(Wg + (size_t)r * 384 + c8 * 8) = tmp.v;
  } else if (bid < 8448) {                // zero hs[0]
    u32 u = (u32)(bid - 8384) * 256u + tid;  // < 16384
    ((uint4*)hs)[u] = make_uint4(0, 0, 0, 0);
  } else if (bid < 9236) {                // W1t[k][n] = W1[n][k]
    u32 u = (u32)(bid - 8448) * 256u + tid;  // < 201728
    u32 k = u / 512u, nn = u % 512u;
    W1t[u] = W1[(size_t)nn * KMLP + k];
  } else if (bid == 9236) {               // bb, cnt, uw
    for (int i = tid; i < 1024; i += 256) bb[i] = b_ih[i] + b_hh[i];
    for (int i = tid; i < 1024; i += 256) cnt[i] = 0u;
    if (tid < 40) {
      float w0 = qw[tid * 3 + 0], w1 = qw[tid * 3 + 1], w2 = qw[tid * 3 + 2];
      float c0 = cosf(0.5f * w0), s0 = sinf(0.5f * w0);
      float c1 = cosf(0.5f * w1), s1 = sinf(0.5f * w1);
      float c2 = cosf(0.5f * w2), s2 = sinf(0.5f * w2);
      float2 e0m = make_float2(c0, -s0), e0p = make_float2(c0, s0);
      float2 e2m = make_float2(c2, -s2), e2p = make_float2(c2, s2);
      // T1 = RY(w1) @ RZ(w0)
      float2 t00 = make_float2(c1 * e0m.x, c1 * e0m.y);
      float2 t01 = make_float2(-s1 * e0p.x, -s1 * e0p.y);
      float2 t10 = make_float2(s1 * e0m.x, s1 * e0m.y);
      float2 t11 = make_float2(c1 * e0p.x, c1 * e0p.y);
      // U = RZ(w2) @ T1
      float2 u00 = cmul(e2m, t00), u01 = cmul(e2m, t01);
      float2 u10 = cmul(e2p, t10), u11 = cmul(e2p, t11);
      float* o = uw + tid * 8;
      o[0] = u00.x; o[1] = u00.y; o[2] = u01.x; o[3] = u01.y;
      o[4] = u10.x; o[5] = u10.y; o[6] = u11.x; o[7] = u11.y;
    }
  } else if (bid <= 9238) {               // bkp = Wk @ proj_b + bk
    int o = (bid - 9237) * 256 + tid;
    if (o < E_) {
      float acc = ipb[E_ + o];
      for (int e = 0; e < E_; ++e) acc += ipw[(size_t)(E_ + o) * E_ + e] * projb[e];
      bkp[o] = acc;
    }
  } else {                                // bvp = Wv @ proj_b + bv
    int o = (bid - 9239) * 256 + tid;
    if (o < E_) {
      float acc = ipb[2 * E_ + o];
      for (int e = 0; e < E_; ++e) acc += ipw[(size_t)(2 * E_ + o) * E_ + e] * projb[e];
      bvp[o] = acc;
    }
  }
}

// ---------------------------------------------------------------------------
// k_lstm, extended grid: blocks 0..255 = EXACT R0 LSTM body (proven optimum)
// at s_setprio(1); blocks 256..511 = prep2+prep3 at default priority 0,
// co-resident (2 blocks/CU), hidden in the LSTM's MALL-stall time.
// R9 de-congestion: prep3 restructured to cut aux17 MALL traffic ~100x —
// prep3b's per-thread broadcast loads of Wvp[:,jj] (R8: ~160K/block) are
// replaced by one cooperative LDS staging pass (320 loads/block); prep3a
// does a single Wkp pass with dual accumulators + LDS-staged ipw columns.
// ---------------------------------------------------------------------------
struct LstmArgs {
  const u16* xbf; u16* hs; const u16* Wg; const float* bb; u32* cnt;
  const float* ipw; const float* ipb; const float* projW;
  const float* opw; const float* opb;
  const float* bkp; const float* bvp;
  float* Wkp; float* Wvp;
  float* WuT; float* bu; float* wd; float* ddp; float* Wovt; float* bov;
};

__launch_bounds__(256, 1)
__global__ void k_lstm(LstmArgs A) {
  const int tid = threadIdx.x;
  __shared__ __align__(16) u16 Wl[32 * 392];  // 32 gate rows x 384 K, pad to 392

  if (blockIdx.x >= 256) {
    // ================= prep blocks (hidden under the LSTM) =================
    const int p = blockIdx.x - 256;           // 0..255
    const v4i kp_srd = make_srd(A.Wkp);
    const v4i vp_srd = make_srd(A.Wvp);
    float* lds_f = (float*)Wl;                // reuse the 25KB LDS as float[]
    // --- prep2: Wkp[o][tid], Wvp[o][tid] (fused; shared projW column) ---
    for (int o = p; o < E_; o += 256) {
      const float* rk = A.ipw + (size_t)(E_ + o) * E_;
      const float* rv = A.ipw + (size_t)(2 * E_ + o) * E_;
      float ak = 0.f, av = 0.f;
#pragma unroll 4
      for (int e = 0; e < E_; ++e) {
        float pw = A.projW[(size_t)e * H_ + tid];
        ak += rk[e] * pw;
        av += rv[e] * pw;
      }
      llvm_amdgcn_raw_buffer_store_f32(ak, kp_srd, (o * H_ + tid) * 4, 0, 17);
      llvm_amdgcn_raw_buffer_store_f32(av, vp_srd, (o * H_ + tid) * 4, 0, 17);
    }
    // --- one-shot barrier among the 256 prep blocks (R0 chain) ---
    __syncthreads();   // implicit vmcnt(0): aux17 stores at MALL
    if (tid == 0) {
      u32* pc = A.cnt + 768;
      __hip_atomic_fetch_add(pc, 1u, __ATOMIC_RELAXED, __HIP_MEMORY_SCOPE_AGENT);
      int guard = 0;
      while (__hip_atomic_load(pc, __ATOMIC_RELAXED, __HIP_MEMORY_SCOPE_AGENT) < 256u) {
        __builtin_amdgcn_s_sleep(1);
        if (++guard > (1 << 24)) break;
      }
    }
    __syncthreads();
    // --- prep3a: WuT[e][tid] = sum_o Wkp[o][tid] * Wq[o][e] for e in {p, p+256}
    //     single Wkp pass (dual acc), ipw columns LDS-staged ---
    const int e0 = p, e1 = p + 256;
    for (int o = tid; o < E_; o += 256) {
      lds_f[o]      = A.ipw[(size_t)o * E_ + e0];
      lds_f[E_ + o] = (e1 < E_) ? A.ipw[(size_t)o * E_ + e1] : 0.f;
    }
    __syncthreads();
    {
      float a0 = 0.f, a1 = 0.f;
#pragma unroll 8
      for (int o = 0; o < E_; ++o) {
        float kv = llvm_amdgcn_raw_buffer_load_f32(kp_srd, (o * H_ + tid) * 4, 0, 17);
        a0 += kv * lds_f[o];
        a1 += kv * lds_f[E_ + o];
      }
      A.WuT[(size_t)e0 * H_ + tid] = a0;          // plain store: next kernel reads
      if (e1 < E_) A.WuT[(size_t)e1 * H_ + tid] = a1;
    }
    // --- prep3b: Wovt[jj][i] = sum_o opw[i][o] * Wvp[o][jj]  (jj = p) ---
    //     Wvp column LDS-staged once (320 aux17 loads, was ~160K broadcasts)
    for (int o = tid; o < E_; o += 256)
      lds_f[2 * E_ + o] = llvm_amdgcn_raw_buffer_load_f32(vp_srd, (o * H_ + p) * 4, 0, 17);
    __syncthreads();
    {
      const int jj = p;
      for (int i = tid; i < E_; i += 256) {
        const float* wo = A.opw + (size_t)i * E_;
        float acc = 0.f;
#pragma unroll 8
        for (int o = 0; o < E_; ++o) acc += wo[o] * lds_f[2 * E_ + o];
        A.Wovt[(size_t)jj * E_ + i] = acc;
      }
    }
    // --- prep3c (block 0 only): bu, wd, ddp, bov ---
    if (p == 0) {
      {
        float acc = 0.f;
#pragma unroll 4
        for (int o = 0; o < E_; ++o) {
          float kv = llvm_amdgcn_raw_buffer_load_f32(kp_srd, (o * H_ + tid) * 4, 0, 17);
          acc += kv * A.ipb[o];
        }
        A.bu[tid] = acc;
      }
      for (int idx = tid; idx < E_; idx += 256) {
        float a1 = 0.f, a2 = A.opb[idx];
#pragma unroll 4
        for (int o = 0; o < E_; ++o) {
          a1 += A.ipw[(size_t)o * E_ + idx] * A.bkp[o];
          a2 += A.opw[(size_t)idx * E_ + o] * A.bvp[o];
        }
        A.wd[idx] = a1; A.bov[idx] = a2;
      }
      if (tid == 0) {
        float acc = 0.f;
        for (int o = 0; o < E_; ++o) acc += A.ipb[o] * A.bkp[o];
        A.ddp[0] = acc;
      }
    }
    return;
  }

  // ======================= LSTM blocks (exact R0 body) =====================
  __builtin_amdgcn_s_setprio(1);   // latency-critical role: issue preference
                                   // over co-resident prep waves (prio 0)
  const int g   = blockIdx.x & 7;
  const int n   = blockIdx.x >> 3;            // 0..31
  const int wid = tid >> 6, lane = tid & 63;

  for (int idx = tid; idx < 32 * 48; idx += 256) {
    int ln = idx / 48, c8 = idx % 48;
    int gr = (ln >> 3) * 256 + n * 8 + (ln & 7);
    *(uint4*)&Wl[ln * 392 + c8 * 8] = *(const uint4*)&A.Wg[(size_t)gr * 384 + c8 * 8];
  }
  const int j  = lane & 7;
  const int gc = n * 8 + j;
  const float bbi = A.bb[gc], bbf2 = A.bb[256 + gc];
  const float bbg = A.bb[512 + gc], bbo = A.bb[768 + gc];

  const int quad = lane >> 4;
  const int mrow = lane & 15;
  const int brow = g * 64 + wid * 16 + mrow;
  const int erow0 = g * 64 + wid * 16 + quad * 4;
  const bool hi = (lane & 8) != 0;
  float crs[4] = {0.f, 0.f, 0.f, 0.f};
  u32* mycnt = A.cnt + g * 64;
  u32 target = 0;

  const v4i hs_srd = make_srd(A.hs);
  const int hvoff = (brow * H_ + quad * 8) * 2;   // per-lane byte offset in a step-block

  // prologue: x[0]
  uint4 xc0, xc1, xc2, xc3, xn0, xn1, xn2, xn3;
  {
    const u16* xb = A.xbf + ((size_t)0 * B_ + brow) * DIN + quad * 8;
    xc0 = *(const uint4*)(xb + 0);
    xc1 = *(const uint4*)(xb + 32);
    xc2 = *(const uint4*)(xb + 64);
    xc3 = *(const uint4*)(xb + 96);
  }
  __syncthreads();  // Wl staged

  for (int t = 0; t < T_; ++t) {
    // h_t loads: coherent (sc0|sc1) pipelined buffer loads
    const int hsoff = t * (B_ * H_ * 2);
    uint4 h0 = __builtin_bit_cast(uint4, llvm_amdgcn_raw_buffer_load_v4i32(hs_srd, hvoff +   0, hsoff, 17));
    uint4 h1 = __builtin_bit_cast(uint4, llvm_amdgcn_raw_buffer_load_v4i32(hs_srd, hvoff +  64, hsoff, 17));
    uint4 h2 = __builtin_bit_cast(uint4, llvm_amdgcn_raw_buffer_load_v4i32(hs_srd, hvoff + 128, hsoff, 17));
    uint4 h3 = __builtin_bit_cast(uint4, llvm_amdgcn_raw_buffer_load_v4i32(hs_srd, hvoff + 192, hsoff, 17));
    uint4 h4 = __builtin_bit_cast(uint4, llvm_amdgcn_raw_buffer_load_v4i32(hs_srd, hvoff + 256, hsoff, 17));
    uint4 h5 = __builtin_bit_cast(uint4, llvm_amdgcn_raw_buffer_load_v4i32(hs_srd, hvoff + 320, hsoff, 17));
    uint4 h6 = __builtin_bit_cast(uint4, llvm_amdgcn_raw_buffer_load_v4i32(hs_srd, hvoff + 384, hsoff, 17));
    uint4 h7 = __builtin_bit_cast(uint4, llvm_amdgcn_raw_buffer_load_v4i32(hs_srd, hvoff + 448, hsoff, 17));
    // x[t+1] prefetch (plain cached loads; drained by the barrier's vmcnt(0))
    {
      const int tn = (t + 1 < T_) ? (t + 1) : t;
      const u16* xb = A.xbf + ((size_t)tn * B_ + brow) * DIN + quad * 8;
      xn0 = *(const uint4*)(xb + 0);
      xn1 = *(const uint4*)(xb + 32);
      xn2 = *(const uint4*)(xb + 64);
      xn3 = *(const uint4*)(xb + 96);
    }

    f32x4 acc0 = {0.f, 0.f, 0.f, 0.f}, acc1 = {0.f, 0.f, 0.f, 0.f};
#define MMSTEP(AV, KOFF)                                                          \
    {                                                                             \
      short8 av  = __builtin_bit_cast(short8, AV);                                \
      short8 bv0 = __builtin_bit_cast(short8,                                     \
          *(const uint4*)&Wl[mrow * 392 + (KOFF) + quad * 8]);                    \
      short8 bv1 = __builtin_bit_cast(short8,                                     \
          *(const uint4*)&Wl[(16 + mrow) * 392 + (KOFF) + quad * 8]);             \
      acc0 = __builtin_amdgcn_mfma_f32_16x16x32_bf16(av, bv0, acc0, 0, 0, 0);     \
      acc1 = __builtin_amdgcn_mfma_f32_16x16x32_bf16(av, bv1, acc1, 0, 0, 0);     \
    }
    MMSTEP(xc0, 0)   MMSTEP(xc1, 32)  MMSTEP(xc2, 64)  MMSTEP(xc3, 96)
    MMSTEP(h0, 128)  MMSTEP(h1, 160)  MMSTEP(h2, 192)  MMSTEP(h3, 224)
    MMSTEP(h4, 256)  MMSTEP(h5, 288)  MMSTEP(h6, 320)  MMSTEP(h7, 352)
#undef MMSTEP

    // epilogue: lanes bit3=0 hold i (tile0) & g (tile1); bit3=1 hold f & o
    const int hsoff_o = (t + 1) * (B_ * H_ * 2);
#pragma unroll
    for (int r = 0; r < 4; ++r) {
      float x0 = acc0[r], x1v = acc1[r];
      float y0 = __shfl_xor(x0, 8, 64);
      float y1 = __shfl_xor(x1v, 8, 64);
      float iv = (hi ? y0 : x0) + bbi;
      float fv = (hi ? x0 : y0) + bbf2;
      float gv = (hi ? y1 : x1v) + bbg;
      float ov = (hi ? x1v : y1) + bbo;
      float cc = sigf(fv) * crs[r] + sigf(iv) * tanhfast(gv);
      crs[r] = cc;
      float hh = sigf(ov) * tanhfast(cc);
      float hh2 = __shfl_xor(hh, 1, 64);      // partner column's h
      if (!hi && ((j & 1) == 0)) {
        u32 pk = (u32)f2b(hh) | ((u32)f2b(hh2) << 16);
        llvm_amdgcn_raw_buffer_store_i32((int)pk, hs_srd,
                                         ((erow0 + r) * H_ + gc) * 2, hsoff_o, 17);
      }
    }
    // ---- group barrier (release h_t, acquire peers' h_t) ----
    target += 32;
    if (t != T_ - 1) {
      __syncthreads();   // implicit vmcnt(0): h stores at MALL, x prefetch done
      if (tid == 0) {
        __hip_atomic_fetch_add(mycnt, 1u, __ATOMIC_RELAXED, __HIP_MEMORY_SCOPE_AGENT);
        int guard = 0;
        while (__hip_atomic_load(mycnt, __ATOMIC_RELAXED, __HIP_MEMORY_SCOPE_AGENT) < target) {
          __builtin_amdgcn_s_sleep(1);
          if (++guard > (1 << 24)) break;
        }
      }
      __syncthreads();
      xc0 = xn0; xc1 = xn1; xc2 = xn2; xc3 = xn3;
    }
  }
}

// ---------------------------------------------------------------------------
// k_post: fused tail. All matvec phases with 2 independent accumulator
// streams + unroll 8 (16 loads in flight) — R7 diagnosis: these loops were
// LATENCY-bound with default codegen.
// ---------------------------------------------------------------------------
__global__ void k_post(const u16* __restrict__ hs, const float* __restrict__ s,
                       const float* __restrict__ WuT, const float* __restrict__ bu,
                       const float* __restrict__ wd, const float* __restrict__ ddp,
                       const float* __restrict__ Wovt, const float* __restrict__ bov,
                       const float* __restrict__ uwg,
                       const float* __restrict__ W1t, const float* __restrict__ b1,
                       const float* __restrict__ W2, const float* __restrict__ b2,
                       float* __restrict__ out) {
  int b = blockIdx.x, tid = threadIdx.x;
  int wid = tid >> 6, lane = tid & 63;
  __shared__ float z[E_];
  __shared__ float red[256];
  __shared__ float ul_s[H_];
  __shared__ float sc[T_];
  __shared__ float wv_s[H_];
  __shared__ float mst_l[DM];
  __shared__ float dvec_s;
  __shared__ float2 psi[1024];
  __shared__ float ang[40];
  __shared__ float uwl[320];
  __shared__ float part[4][10];
  __shared__ float qf_s[10];
  __shared__ float mg[KMLP];
  __shared__ float x1[NL1];

  // ---- phase A (k_u): u_b and d_b ----
  z[tid] = b2f(hs[((size_t)T_ * B_ + b) * H_ + tid]);
  if (tid < F_) z[H_ + tid] = s[(size_t)b * F_ + tid];
  __syncthreads();
  {
    float a0 = bu[tid], a1 = 0.f;
#pragma unroll 8
    for (int e = 0; e < 160; ++e) {
      a0 += WuT[(size_t)e * H_ + tid] * z[e];
      a1 += WuT[(size_t)(e + 160) * H_ + tid] * z[e + 160];
    }
    ul_s[tid] = a0 + a1;
    float p = 0.f;
    for (int e = tid; e < E_; e += 256) p += wd[e] * z[e];
    red[tid] = p;
    __syncthreads();
    for (int s2 = 128; s2 > 0; s2 >>= 1) {
      if (tid < s2) red[tid] += red[tid + s2];
      __syncthreads();
    }
    if (tid == 0) dvec_s = red[0] + ddp[0];
    __syncthreads();
  }

  // ---- phase B (k_aw): scores -> softmax -> wv ----
  {
    const float db = dvec_s;
    const float scale = 0.055901699437494745f;  // 1/sqrt(320)
    float4 ul = make_float4(ul_s[lane * 4], ul_s[lane * 4 + 1],
                            ul_s[lane * 4 + 2], ul_s[lane * 4 + 3]);
    for (int tt = 0; tt < 64; ++tt) {
      int t = wid * 64 + tt;
      u32 rw0 = ((const u32*)(hs + ((size_t)(t + 1) * B_ + b) * H_))[lane * 2];
      u32 rw1 = ((const u32*)(hs + ((size_t)(t + 1) * B_ + b) * H_))[lane * 2 + 1];
      union { u32 uu; float f; } f0, f1, f2, f3;
      f0.uu = rw0 << 16; f1.uu = rw0 & 0xFFFF0000u;
      f2.uu = rw1 << 16; f3.uu = rw1 & 0xFFFF0000u;
      float p = f0.f * ul.x + f1.f * ul.y + f2.f * ul.z + f3.f * ul.w;
#pragma unroll
      for (int off = 32; off > 0; off >>= 1) p += __shfl_xor(p, off, 64);
      if (lane == 0) sc[t] = (p + db) * scale;
    }
    __syncthreads();
    float v = sc[tid];
    red[tid] = v;
    __syncthreads();
    for (int s2 = 128; s2 > 0; s2 >>= 1) {
      if (tid < s2) red[tid] = fmaxf(red[tid], red[tid + s2]);
      __syncthreads();
    }
    float m = red[0];
    __syncthreads();
    float e = __expf(v - m);
    red[tid] = e;
    __syncthreads();
    for (int s2 = 128; s2 > 0; s2 >>= 1) {
      if (tid < s2) red[tid] += red[tid + s2];
      __syncthreads();
    }
    float inv = 1.f / red[0];
    __syncthreads();
    sc[tid] = e * inv;
    __syncthreads();
    float a0 = 0.f, a1 = 0.f;
#pragma unroll 8
    for (int t = 0; t < 128; ++t) {
      a0 += sc[t]       * b2f(hs[((size_t)(t + 1) * B_ + b) * H_ + tid]);
      a1 += sc[t + 128] * b2f(hs[((size_t)(t + 129) * B_ + b) * H_ + tid]);
    }
    wv_s[tid] = a0 + a1;
    __syncthreads();
  }

  // ---- phase C (k_ao): merged_state = [Wov @ w_b + bov, s_b] ----
  {
    for (int i = tid; i < E_; i += 256) {
      float a0 = bov[i], a1 = 0.f;
#pragma unroll 8
      for (int jj = 0; jj < 128; ++jj) {
        a0 += Wovt[(size_t)jj * E_ + i] * wv_s[jj];
        a1 += Wovt[(size_t)(jj + 128) * E_ + i] * wv_s[jj + 128];
      }
      mst_l[i] = a0 + a1;
    }
    if (tid < F_) mst_l[E_ + tid] = s[(size_t)b * F_ + tid];
    __syncthreads();
  }

  // ---- phase D (k_vqc): 10-qubit statevector sim ----
  {
    if (tid < 40) ang[tid] = tanhf(mst_l[tid]) * PI_F;
    uwl[tid] = uwg[tid];
    if (tid < 64) uwl[256 + tid] = uwg[256 + tid];
#pragma unroll
    for (int k = 0; k < 4; ++k) psi[tid + k * 256] = make_float2(0.03125f, 0.f);
    __syncthreads();
    for (int l = 0; l < 4; ++l) {
      for (int q = 0; q < 10; ++q) {
        int lq = l * 10 + q;
        float a = ang[lq];
        float ca = __cosf(0.5f * a), sa = __sinf(0.5f * a);
        float cs = ca * sa;
        float2 m00 = make_float2(ca * ca, sa * sa);
        float2 m01 = make_float2(-cs, -cs);
        float2 m10 = make_float2(cs, -cs);
        float2 m11 = make_float2(ca * ca, -sa * sa);
        const float* uwp = &uwl[lq * 8];
        float2 a00 = make_float2(uwp[0], uwp[1]), a01 = make_float2(uwp[2], uwp[3]);
        float2 a10 = make_float2(uwp[4], uwp[5]), a11 = make_float2(uwp[6], uwp[7]);
        float2 u00 = cadd(cmul(a00, m00), cmul(a01, m10));
        float2 u01 = cadd(cmul(a00, m01), cmul(a01, m11));
        float2 u10 = cadd(cmul(a10, m00), cmul(a11, m10));
        float2 u11 = cadd(cmul(a10, m01), cmul(a11, m11));
        int bp = 9 - q;
        __syncthreads();
#pragma unroll
        for (int k = 0; k < 2; ++k) {
          int p = tid + k * 256;
          int i0 = ((p >> bp) << (bp + 1)) | (p & ((1 << bp) - 1));
          int i1 = i0 | (1 << bp);
          float2 A0 = psi[i0], A1 = psi[i1];
          psi[i0] = cadd(cmul(u00, A0), cmul(u01, A1));
          psi[i1] = cadd(cmul(u10, A0), cmul(u11, A1));
        }
      }
      for (int q = 0; q < 9; ++q) {  // CNOT(q, q+1): adjacent bits
        int lo = 8 - q;
        __syncthreads();
        int p = tid;
        int i0 = ((p >> lo) << (lo + 2)) | (2 << lo) | (p & ((1 << lo) - 1));
        int i1 = i0 | (1 << lo);
        float2 tmp = psi[i0]; psi[i0] = psi[i1]; psi[i1] = tmp;
      }
      __syncthreads();  // CNOT(9, 0): ctrl bit0, tgt bit9
      {
        int i0 = (tid << 1) | 1;
        int i1 = i0 | 512;
        float2 tmp = psi[i0]; psi[i0] = psi[i1]; psi[i1] = tmp;
      }
    }
    __syncthreads();
    float acc[10];
#pragma unroll
    for (int q = 0; q < 10; ++q) acc[q] = 0.f;
#pragma unroll
    for (int k = 0; k < 4; ++k) {
      int idx = tid + k * 256;
      float2 A = psi[idx];
      float pr = A.x * A.x + A.y * A.y;
#pragma unroll
      for (int q = 0; q < 10; ++q) acc[q] += ((idx >> (9 - q)) & 1) ? -pr : pr;
    }
#pragma unroll
    for (int q = 0; q < 10; ++q) {
      float vq = acc[q];
#pragma unroll
      for (int off = 32; off > 0; off >>= 1) vq += __shfl_xor(vq, off, 64);
      if (lane == 0) part[wid][q] = vq;
    }
    __syncthreads();
    if (tid < 10) qf_s[tid] = part[0][tid] + part[1][tid] + part[2][tid] + part[3][tid];
  }

  // ---- phase E (k_mlp): x1 = relu([mst,qf] @ W1^T + b1); out = x1 @ W2^T + b2
  {
    for (int i = tid; i < DM; i += 256) mg[i] = mst_l[i];
    if (tid < 10) mg[DM + tid] = qf_s[tid];
    __syncthreads();
    float a0 = b1[tid], a1 = b1[tid + 256];
#pragma unroll 8
    for (int k = 0; k < KMLP; ++k) {
      float m = mg[k];
      a0 += W1t[(size_t)k * NL1 + tid] * m;
      a1 += W1t[(size_t)k * NL1 + tid + 256] * m;
    }
    x1[tid] = fmaxf(a0, 0.f);
    x1[tid + 256] = fmaxf(a1, 0.f);
    __syncthreads();
    int a = tid >> 5, l32 = tid & 31;
    float p = 0.f;
    for (int k = l32; k < NL1; k += 32) p += x1[k] * W2[(size_t)a * NL1 + k];
    red[tid] = p;
    __syncthreads();
    if (tid < 8) {
      float acc = b2[tid];
#pragma unroll
      for (int i = 0; i < 32; ++i) acc += red[tid * 32 + i];
      out[(size_t)b * NACT + tid] = acc;
    }
  }
}

// ---------------------------------------------------------------------------
extern "C" void kernel_launch(void* const* d_in, const int* in_sizes, int n_in,
                              void* d_out, int out_size, void* d_ws, size_t ws_size,
                              hipStream_t stream) {
  const float* s      = (const float*)d_in[0];
  const float* lstm_s = (const float*)d_in[1];
  const float* W_ih   = (const float*)d_in[2];
  const float* W_hh   = (const float*)d_in[3];
  const float* b_ih   = (const float*)d_in[4];
  const float* b_hh   = (const float*)d_in[5];
  const float* projW  = (const float*)d_in[6];
  const float* projb  = (const float*)d_in[7];
  const float* ipw    = (const float*)d_in[8];
  const float* ipb    = (const float*)d_in[9];
  const float* opw    = (const float*)d_in[10];
  const float* opb    = (const float*)d_in[11];
  const float* qw     = (const float*)d_in[12];
  const float* W1     = (const float*)d_in[13];
  const float* b1     = (const float*)d_in[14];
  const float* W2     = (const float*)d_in[15];
  const float* b2     = (const float*)d_in[16];
  float* out = (float*)d_out;

  char* wsb = (char*)d_ws;
  size_t off = 0;
  auto alloc = [&](size_t bytes) -> void* {
    void* p = wsb + off;
    off = (off + bytes + 255) & ~(size_t)255;
    return p;
  };
  u16*  xbf  = (u16*)alloc((size_t)T_ * B_ * DIN * 2);
  u16*  hs   = (u16*)alloc((size_t)(T_ + 1) * B_ * H_ * 2);
  u16*  Wg   = (u16*)alloc((size_t)G4 * 384 * 2);
  float* bb  = (float*)alloc(G4 * 4);
  float* Wkp = (float*)alloc((size_t)E_ * H_ * 4);
  float* Wvp = (float*)alloc((size_t)E_ * H_ * 4);
  float* bkp = (float*)alloc(E_ * 4);
  float* bvp = (float*)alloc(E_ * 4);
  float* WuT = (float*)alloc((size_t)E_ * H_ * 4);
  float* bu  = (float*)alloc(H_ * 4);
  float* wd  = (float*)alloc(E_ * 4);
  float* ddp = (float*)alloc(256);
  float* Wovt= (float*)alloc((size_t)H_ * E_ * 4);
  float* bov = (float*)alloc(E_ * 4);
  float* uw  = (float*)alloc(40 * 8 * 4);
  float* W1t = (float*)alloc((size_t)KMLP * NL1 * 4);
  u32*  cnt  = (u32*)alloc(1024 * 4);
  (void)ws_size; (void)in_sizes; (void)n_in; (void)out_size;

  hipLaunchKernelGGL(k_prep1, dim3(9241), dim3(256), 0, stream,
                     lstm_s, W_ih, W_hh, b_ih, b_hh, ipw, ipb, projb, qw, W1,
                     xbf, hs, Wg, bb, W1t, uw, bkp, bvp, cnt);

  LstmArgs la;
  la.xbf = xbf; la.hs = hs; la.Wg = Wg; la.bb = bb; la.cnt = cnt;
  la.ipw = ipw; la.ipb = ipb; la.projW = projW; la.opw = opw; la.opb = opb;
  la.bkp = bkp; la.bvp = bvp; la.Wkp = Wkp; la.Wvp = Wvp;
  la.WuT = WuT; la.bu = bu; la.wd = wd; la.ddp = ddp; la.Wovt = Wovt; la.bov = bov;
  void* kargs[] = { (void*)&la };
  hipError_t ce = hipLaunchCooperativeKernel(reinterpret_cast<const void*>(&k_lstm),
                                             dim3(512), dim3(256), kargs, 0, stream);
  if (ce != hipSuccess) {
    // fallback: plain launch (512 blocks at 2/CU co-schedule in practice)
    hipLaunchKernelGGL(k_lstm, dim3(512), dim3(256), 0, stream, la);
  }

  hipLaunchKernelGGL(k_post, dim3(512), dim3(256), 0, stream,
                     hs, s, WuT, bu, wd, ddp, Wovt, bov, uw, W1t, b1, W2, b2, out);
}

// Round 10
// 1176.192 us; speedup vs baseline: 2.4619x; 1.0063x over previous
//
#include <hip/hip_runtime.h>
#include <hip/hip_bf16.h>
#include <math.h>

typedef unsigned int u32;
typedef unsigned long long u64;
typedef unsigned short u16;
typedef __attribute__((ext_vector_type(8))) short short8;
typedef __attribute__((ext_vector_type(4))) float f32x4;
typedef __attribute__((ext_vector_type(4))) int v4i;

#define PI_F 3.14159265358979f
#define B_   512
#define T_   256
#define DIN  128
#define H_   256
#define G4   1024
#define F_   64
#define E_   320
#define DM   384
#define NL1  512
#define NACT 8
#define KMLP 394

// Raw buffer intrinsics (CK idiom) with explicit cache policy. aux=17 =
// sc0|sc1: bypass L1+L2, read/write at the device coherence point (MALL).
// The ONLY scope proven (R0-R9) for cross-block store->load visibility.
// R0's barrier (syncthreads-drain -> agent atomicAdd -> tid0 poll ->
// syncthreads) is the empirical optimum for cross-CU sync; every
// alternative tried (sentinel R1/R3/R6, SC0-only R2, flags R4, sharded R5)
// measured worse. R10: prep work refactored so it needs NO aux17 traffic
// at all (see prep comment) — MALL stays reserved for the LSTM.
__device__ v4i llvm_amdgcn_raw_buffer_load_v4i32(v4i rsrc, int voffset,
                                                 int soffset, int aux)
    __asm("llvm.amdgcn.raw.buffer.load.v4i32");
__device__ void llvm_amdgcn_raw_buffer_store_i32(int vdata, v4i rsrc,
                                                 int voffset, int soffset,
                                                 int aux)
    __asm("llvm.amdgcn.raw.buffer.store.i32");

__device__ __forceinline__ v4i make_srd(const void* p) {
  v4i r;
  r.x = (int)(u32)(u64)p;
  r.y = (int)(u32)((u64)p >> 32);   // base hi, stride=0
  r.z = (int)0xFFFFFFFFu;           // num_records: bounds check disabled
  r.w = 0x00020000;                 // raw untyped dword access
  return r;
}

__device__ __forceinline__ float b2f(u16 h) {
  union { u32 u; float f; } v; v.u = ((u32)h) << 16; return v.f;
}
__device__ __forceinline__ u16 f2b(float f) {
  union { float f; u32 u; } v; v.f = f;
  u32 r = (v.u + 0x7FFFu + ((v.u >> 16) & 1u)) >> 16;
  return (u16)r;
}
__device__ __forceinline__ float sigf(float x) { return 1.0f / (1.0f + __expf(-x)); }
__device__ __forceinline__ float tanhfast(float x) { return 2.0f / (1.0f + __expf(-2.0f * x)) - 1.0f; }
__device__ __forceinline__ float2 cmul(float2 a, float2 b) {
  return make_float2(a.x * b.x - a.y * b.y, a.x * b.y + a.y * b.x);
}
__device__ __forceinline__ float2 cadd(float2 a, float2 b) {
  return make_float2(a.x + b.x, a.y + b.y);
}

// ---------------------------------------------------------------------------
// prep1: x transpose+bf16, Wg=[W_ih|W_hh] bf16, zero hs[0], bb, uw, bkp,
// bvp, zero barrier counters. (W1t transpose moved into k_lstm prep blocks.)
// ---------------------------------------------------------------------------
__global__ void k_prep1(const float* __restrict__ lstm_s,
                        const float* __restrict__ W_ih,
                        const float* __restrict__ W_hh,
                        const float* __restrict__ b_ih,
                        const float* __restrict__ b_hh,
                        const float* __restrict__ ipw,
                        const float* __restrict__ ipb,
                        const float* __restrict__ projb,
                        const float* __restrict__ qw,
                        u16* __restrict__ xbf,
                        u16* __restrict__ hs,
                        u16* __restrict__ Wg,
                        float* __restrict__ bb,
                        float* __restrict__ uw,
                        float* __restrict__ bkp,
                        float* __restrict__ bvp,
                        u32* __restrict__ cnt) {
  const int bid = blockIdx.x;
  const int tid = threadIdx.x;
  if (bid < 8192) {                       // lstm_s (B,T,128) -> xbf (T,B,128) bf16
    u32 u = (u32)bid * 256u + tid;        // < 2097152 uint4 units
    u32 c8 = u & 15u, b = (u >> 4) & 511u, t = u >> 13;
    const float* src = lstm_s + ((size_t)b * T_ + t) * DIN + c8 * 8;
    union { u16 h[8]; uint4 v; } tmp;
#pragma unroll
    for (int i = 0; i < 8; ++i) tmp.h[i] = f2b(src[i]);
    *(uint4*)(xbf + ((size_t)t * B_ + b) * DIN + c8 * 8) = tmp.v;
  } else if (bid < 8384) {                // Wg (1024 x 384) bf16
    u32 u = (u32)(bid - 8192) * 256u + tid;  // < 49152
    u32 c8 = u % 48u, r = u / 48u;
    const float* src = (c8 < 16) ? (W_ih + (size_t)r * DIN + c8 * 8)
                                 : (W_hh + (size_t)r * H_ + (c8 - 16) * 8);
    union { u16 h[8]; uint4 v; } tmp;
#pragma unroll
    for (int i = 0; i < 8; ++i) tmp.h[i] = f2b(src[i]);
    *(uint4*)(Wg + (size_t)r * 384 + c8 * 8) = tmp.v;
  } else if (bid < 8448) {                // zero hs[0]
    u32 u = (u32)(bid - 8384) * 256u + tid;  // < 16384
    ((uint4*)hs)[u] = make_uint4(0, 0, 0, 0);
  } else if (bid == 8448) {               // bb, cnt, uw
    for (int i = tid; i < 1024; i += 256) bb[i] = b_ih[i] + b_hh[i];
    for (int i = tid; i < 1024; i += 256) cnt[i] = 0u;
    if (tid < 40) {
      float w0 = qw[tid * 3 + 0], w1 = qw[tid * 3 + 1], w2 = qw[tid * 3 + 2];
      float c0 = cosf(0.5f * w0), s0 = sinf(0.5f * w0);
      float c1 = cosf(0.5f * w1), s1 = sinf(0.5f * w1);
      float c2 = cosf(0.5f * w2), s2 = sinf(0.5f * w2);
      float2 e0m = make_float2(c0, -s0), e0p = make_float2(c0, s0);
      float2 e2m = make_float2(c2, -s2), e2p = make_float2(c2, s2);
      // T1 = RY(w1) @ RZ(w0)
      float2 t00 = make_float2(c1 * e0m.x, c1 * e0m.y);
      float2 t01 = make_float2(-s1 * e0p.x, -s1 * e0p.y);
      float2 t10 = make_float2(s1 * e0m.x, s1 * e0m.y);
      float2 t11 = make_float2(c1 * e0p.x, c1 * e0p.y);
      // U = RZ(w2) @ T1
      float2 u00 = cmul(e2m, t00), u01 = cmul(e2m, t01);
      float2 u10 = cmul(e2p, t10), u11 = cmul(e2p, t11);
      float* o = uw + tid * 8;
      o[0] = u00.x; o[1] = u00.y; o[2] = u01.x; o[3] = u01.y;
      o[4] = u10.x; o[5] = u10.y; o[6] = u11.x; o[7] = u11.y;
    }
  } else if (bid <= 8450) {               // bkp = Wk @ proj_b + bk
    int o = (bid - 8449) * 256 + tid;
    if (o < E_) {
      float acc = ipb[E_ + o];
      for (int e = 0; e < E_; ++e) acc += ipw[(size_t)(E_ + o) * E_ + e] * projb[e];
      bkp[o] = acc;
    }
  } else {                                // bvp = Wv @ proj_b + bv
    int o = (bid - 8451) * 256 + tid;
    if (o < E_) {
      float acc = ipb[2 * E_ + o];
      for (int e = 0; e < E_; ++e) acc += ipw[(size_t)(2 * E_ + o) * E_ + e] * projb[e];
      bvp[o] = acc;
    }
  }
}

// ---------------------------------------------------------------------------
// k_lstm, extended grid: blocks 0..255 = EXACT R0 LSTM body (proven optimum)
// at s_setprio(1); blocks 256..511 = prep work at priority 0, co-resident
// (2 blocks/CU), hidden in the LSTM's MALL-stall time.
// R10: prep refactored to a block-local factored form with ZERO aux17
// traffic and NO inter-block barrier:
//   WuT[e][:]  = M[e][:] @ projW,  M[e][:]  = sum_o Wq[o][e] * Wk[o][:]
//   Wovt[:,i]  = projW^T @ N[i][:], N[i][:] = sum_o opw[i][o] * Wv[o][:]
//   bu         = projW^T @ (Wk^T ipb)
// M/N rows live in LDS per block; all global reads are plain cacheable
// input loads (ipw/opw/projW fit in L2, shared by co-resident blocks).
// Algebraically identical to the old Wkp/Wvp composition (f32 reassoc only).
// ---------------------------------------------------------------------------
struct LstmArgs {
  const u16* xbf; u16* hs; const u16* Wg; const float* bb; u32* cnt;
  const float* ipw; const float* ipb; const float* projW;
  const float* opw; const float* opb;
  const float* bkp; const float* bvp;
  const float* W1; float* W1t;
  float* WuT; float* bu; float* wd; float* ddp; float* Wovt; float* bov;
};

__launch_bounds__(256, 1)
__global__ void k_lstm(LstmArgs A) {
  const int tid = threadIdx.x;
  __shared__ __align__(16) u16 Wl[32 * 392];  // 32 gate rows x 384 K, pad to 392

  if (blockIdx.x >= 256) {
    // ================= prep blocks (hidden under the LSTM) =================
    const int p = blockIdx.x - 256;           // 0..255
    float* lds_f = (float*)Wl;                // 320 floats of M/N row

    // --- W1t[k][n] = W1[n][k]  (KMLP*NL1 = 201728 elements, strided) ---
    for (u32 u = (u32)p * 256u + tid; u < (u32)KMLP * NL1; u += 65536u) {
      u32 k = u / 512u, nn = u % 512u;
      A.W1t[u] = A.W1[(size_t)nn * KMLP + k];
    }

    // --- WuT rows e = p (and p+256): M[e][:] then @ projW ---
    for (int e = p; e < E_; e += 256) {
      for (int e2 = tid; e2 < E_; e2 += 256) {
        float m0 = 0.f, m1 = 0.f;
#pragma unroll 8
        for (int o = 0; o < E_; o += 2) {
          m0 += A.ipw[(size_t)o * E_ + e]       * A.ipw[(size_t)(E_ + o) * E_ + e2];
          m1 += A.ipw[(size_t)(o + 1) * E_ + e] * A.ipw[(size_t)(E_ + o + 1) * E_ + e2];
        }
        lds_f[e2] = m0 + m1;
      }
      __syncthreads();
      {
        float a0 = 0.f, a1 = 0.f;
#pragma unroll 8
        for (int e2 = 0; e2 < E_; e2 += 2) {
          a0 += lds_f[e2]     * A.projW[(size_t)e2 * H_ + tid];
          a1 += lds_f[e2 + 1] * A.projW[(size_t)(e2 + 1) * H_ + tid];
        }
        A.WuT[(size_t)e * H_ + tid] = a0 + a1;
      }
      __syncthreads();
    }

    // --- Wovt columns i = p (and p+256): N[i][:] then projW^T ---
    for (int i = p; i < E_; i += 256) {
      const float* wo = A.opw + (size_t)i * E_;
      for (int e2 = tid; e2 < E_; e2 += 256) {
        float m0 = 0.f, m1 = 0.f;
#pragma unroll 8
        for (int o = 0; o < E_; o += 2) {
          m0 += wo[o]     * A.ipw[(size_t)(2 * E_ + o) * E_ + e2];
          m1 += wo[o + 1] * A.ipw[(size_t)(2 * E_ + o + 1) * E_ + e2];
        }
        lds_f[e2] = m0 + m1;
      }
      __syncthreads();
      {
        float a0 = 0.f, a1 = 0.f;
#pragma unroll 8
        for (int e2 = 0; e2 < E_; e2 += 2) {
          a0 += lds_f[e2]     * A.projW[(size_t)e2 * H_ + tid];
          a1 += lds_f[e2 + 1] * A.projW[(size_t)(e2 + 1) * H_ + tid];
        }
        A.Wovt[(size_t)tid * E_ + i] = a0 + a1;   // jj = tid
      }
      __syncthreads();
    }

    // --- block p==0: bu (factored), wd, ddp, bov ---
    if (p == 0) {
      for (int e2 = tid; e2 < E_; e2 += 256) {   // vk = Wk^T ipb
        float acc = 0.f;
#pragma unroll 4
        for (int o = 0; o < E_; ++o)
          acc += A.ipb[o] * A.ipw[(size_t)(E_ + o) * E_ + e2];
        lds_f[e2] = acc;
      }
      __syncthreads();
      {
        float a0 = 0.f;
#pragma unroll 4
        for (int e2 = 0; e2 < E_; ++e2)
          a0 += lds_f[e2] * A.projW[(size_t)e2 * H_ + tid];
        A.bu[tid] = a0;
      }
      for (int idx = tid; idx < E_; idx += 256) {
        float a1 = 0.f, a2 = A.opb[idx];
#pragma unroll 4
        for (int o = 0; o < E_; ++o) {
          a1 += A.ipw[(size_t)o * E_ + idx] * A.bkp[o];
          a2 += A.opw[(size_t)idx * E_ + o] * A.bvp[o];
        }
        A.wd[idx] = a1; A.bov[idx] = a2;
      }
      if (tid == 0) {
        float acc = 0.f;
        for (int o = 0; o < E_; ++o) acc += A.ipb[o] * A.bkp[o];
        A.ddp[0] = acc;
      }
    }
    return;
  }

  // ======================= LSTM blocks (exact R0 body) =====================
  __builtin_amdgcn_s_setprio(1);   // latency-critical role: issue preference
  const int g   = blockIdx.x & 7;
  const int n   = blockIdx.x >> 3;            // 0..31
  const int wid = tid >> 6, lane = tid & 63;

  for (int idx = tid; idx < 32 * 48; idx += 256) {
    int ln = idx / 48, c8 = idx % 48;
    int gr = (ln >> 3) * 256 + n * 8 + (ln & 7);
    *(uint4*)&Wl[ln * 392 + c8 * 8] = *(const uint4*)&A.Wg[(size_t)gr * 384 + c8 * 8];
  }
  const int j  = lane & 7;
  const int gc = n * 8 + j;
  const float bbi = A.bb[gc], bbf2 = A.bb[256 + gc];
  const float bbg = A.bb[512 + gc], bbo = A.bb[768 + gc];

  const int quad = lane >> 4;
  const int mrow = lane & 15;
  const int brow = g * 64 + wid * 16 + mrow;
  const int erow0 = g * 64 + wid * 16 + quad * 4;
  const bool hi = (lane & 8) != 0;
  float crs[4] = {0.f, 0.f, 0.f, 0.f};
  u32* mycnt = A.cnt + g * 64;
  u32 target = 0;

  const v4i hs_srd = make_srd(A.hs);
  const int hvoff = (brow * H_ + quad * 8) * 2;   // per-lane byte offset in a step-block

  // prologue: x[0]
  uint4 xc0, xc1, xc2, xc3, xn0, xn1, xn2, xn3;
  {
    const u16* xb = A.xbf + ((size_t)0 * B_ + brow) * DIN + quad * 8;
    xc0 = *(const uint4*)(xb + 0);
    xc1 = *(const uint4*)(xb + 32);
    xc2 = *(const uint4*)(xb + 64);
    xc3 = *(const uint4*)(xb + 96);
  }
  __syncthreads();  // Wl staged

  for (int t = 0; t < T_; ++t) {
    // h_t loads: coherent (sc0|sc1) pipelined buffer loads
    const int hsoff = t * (B_ * H_ * 2);
    uint4 h0 = __builtin_bit_cast(uint4, llvm_amdgcn_raw_buffer_load_v4i32(hs_srd, hvoff +   0, hsoff, 17));
    uint4 h1 = __builtin_bit_cast(uint4, llvm_amdgcn_raw_buffer_load_v4i32(hs_srd, hvoff +  64, hsoff, 17));
    uint4 h2 = __builtin_bit_cast(uint4, llvm_amdgcn_raw_buffer_load_v4i32(hs_srd, hvoff + 128, hsoff, 17));
    uint4 h3 = __builtin_bit_cast(uint4, llvm_amdgcn_raw_buffer_load_v4i32(hs_srd, hvoff + 192, hsoff, 17));
    uint4 h4 = __builtin_bit_cast(uint4, llvm_amdgcn_raw_buffer_load_v4i32(hs_srd, hvoff + 256, hsoff, 17));
    uint4 h5 = __builtin_bit_cast(uint4, llvm_amdgcn_raw_buffer_load_v4i32(hs_srd, hvoff + 320, hsoff, 17));
    uint4 h6 = __builtin_bit_cast(uint4, llvm_amdgcn_raw_buffer_load_v4i32(hs_srd, hvoff + 384, hsoff, 17));
    uint4 h7 = __builtin_bit_cast(uint4, llvm_amdgcn_raw_buffer_load_v4i32(hs_srd, hvoff + 448, hsoff, 17));
    // x[t+1] prefetch (plain cached loads; drained by the barrier's vmcnt(0))
    {
      const int tn = (t + 1 < T_) ? (t + 1) : t;
      const u16* xb = A.xbf + ((size_t)tn * B_ + brow) * DIN + quad * 8;
      xn0 = *(const uint4*)(xb + 0);
      xn1 = *(const uint4*)(xb + 32);
      xn2 = *(const uint4*)(xb + 64);
      xn3 = *(const uint4*)(xb + 96);
    }

    f32x4 acc0 = {0.f, 0.f, 0.f, 0.f}, acc1 = {0.f, 0.f, 0.f, 0.f};
#define MMSTEP(AV, KOFF)                                                          \
    {                                                                             \
      short8 av  = __builtin_bit_cast(short8, AV);                                \
      short8 bv0 = __builtin_bit_cast(short8,                                     \
          *(const uint4*)&Wl[mrow * 392 + (KOFF) + quad * 8]);                    \
      short8 bv1 = __builtin_bit_cast(short8,                                     \
          *(const uint4*)&Wl[(16 + mrow) * 392 + (KOFF) + quad * 8]);             \
      acc0 = __builtin_amdgcn_mfma_f32_16x16x32_bf16(av, bv0, acc0, 0, 0, 0);     \
      acc1 = __builtin_amdgcn_mfma_f32_16x16x32_bf16(av, bv1, acc1, 0, 0, 0);     \
    }
    MMSTEP(xc0, 0)   MMSTEP(xc1, 32)  MMSTEP(xc2, 64)  MMSTEP(xc3, 96)
    MMSTEP(h0, 128)  MMSTEP(h1, 160)  MMSTEP(h2, 192)  MMSTEP(h3, 224)
    MMSTEP(h4, 256)  MMSTEP(h5, 288)  MMSTEP(h6, 320)  MMSTEP(h7, 352)
#undef MMSTEP

    // epilogue: lanes bit3=0 hold i (tile0) & g (tile1); bit3=1 hold f & o
    const int hsoff_o = (t + 1) * (B_ * H_ * 2);
#pragma unroll
    for (int r = 0; r < 4; ++r) {
      float x0 = acc0[r], x1v = acc1[r];
      float y0 = __shfl_xor(x0, 8, 64);
      float y1 = __shfl_xor(x1v, 8, 64);
      float iv = (hi ? y0 : x0) + bbi;
      float fv = (hi ? x0 : y0) + bbf2;
      float gv = (hi ? y1 : x1v) + bbg;
      float ov = (hi ? x1v : y1) + bbo;
      float cc = sigf(fv) * crs[r] + sigf(iv) * tanhfast(gv);
      crs[r] = cc;
      float hh = sigf(ov) * tanhfast(cc);
      float hh2 = __shfl_xor(hh, 1, 64);      // partner column's h
      if (!hi && ((j & 1) == 0)) {
        u32 pk = (u32)f2b(hh) | ((u32)f2b(hh2) << 16);
        llvm_amdgcn_raw_buffer_store_i32((int)pk, hs_srd,
                                         ((erow0 + r) * H_ + gc) * 2, hsoff_o, 17);
      }
    }
    // ---- group barrier (release h_t, acquire peers' h_t) ----
    target += 32;
    if (t != T_ - 1) {
      __syncthreads();   // implicit vmcnt(0): h stores at MALL, x prefetch done
      if (tid == 0) {
        __hip_atomic_fetch_add(mycnt, 1u, __ATOMIC_RELAXED, __HIP_MEMORY_SCOPE_AGENT);
        int guard = 0;
        while (__hip_atomic_load(mycnt, __ATOMIC_RELAXED, __HIP_MEMORY_SCOPE_AGENT) < target) {
          __builtin_amdgcn_s_sleep(1);
          if (++guard > (1 << 24)) break;
        }
      }
      __syncthreads();
      xc0 = xn0; xc1 = xn1; xc2 = xn2; xc3 = xn3;
    }
  }
}

// ---------------------------------------------------------------------------
// k_post: fused tail. All matvec phases with 2 independent accumulator
// streams + unroll 8 (16 loads in flight) — R7 diagnosis: these loops were
// LATENCY-bound with default codegen.
// ---------------------------------------------------------------------------
__global__ void k_post(const u16* __restrict__ hs, const float* __restrict__ s,
                       const float* __restrict__ WuT, const float* __restrict__ bu,
                       const float* __restrict__ wd, const float* __restrict__ ddp,
                       const float* __restrict__ Wovt, const float* __restrict__ bov,
                       const float* __restrict__ uwg,
                       const float* __restrict__ W1t, const float* __restrict__ b1,
                       const float* __restrict__ W2, const float* __restrict__ b2,
                       float* __restrict__ out) {
  int b = blockIdx.x, tid = threadIdx.x;
  int wid = tid >> 6, lane = tid & 63;
  __shared__ float z[E_];
  __shared__ float red[256];
  __shared__ float ul_s[H_];
  __shared__ float sc[T_];
  __shared__ float wv_s[H_];
  __shared__ float mst_l[DM];
  __shared__ float dvec_s;
  __shared__ float2 psi[1024];
  __shared__ float ang[40];
  __shared__ float uwl[320];
  __shared__ float part[4][10];
  __shared__ float qf_s[10];
  __shared__ float mg[KMLP];
  __shared__ float x1[NL1];

  // ---- phase A (k_u): u_b and d_b ----
  z[tid] = b2f(hs[((size_t)T_ * B_ + b) * H_ + tid]);
  if (tid < F_) z[H_ + tid] = s[(size_t)b * F_ + tid];
  __syncthreads();
  {
    float a0 = bu[tid], a1 = 0.f;
#pragma unroll 8
    for (int e = 0; e < 160; ++e) {
      a0 += WuT[(size_t)e * H_ + tid] * z[e];
      a1 += WuT[(size_t)(e + 160) * H_ + tid] * z[e + 160];
    }
    ul_s[tid] = a0 + a1;
    float p = 0.f;
    for (int e = tid; e < E_; e += 256) p += wd[e] * z[e];
    red[tid] = p;
    __syncthreads();
    for (int s2 = 128; s2 > 0; s2 >>= 1) {
      if (tid < s2) red[tid] += red[tid + s2];
      __syncthreads();
    }
    if (tid == 0) dvec_s = red[0] + ddp[0];
    __syncthreads();
  }

  // ---- phase B (k_aw): scores -> softmax -> wv ----
  {
    const float db = dvec_s;
    const float scale = 0.055901699437494745f;  // 1/sqrt(320)
    float4 ul = make_float4(ul_s[lane * 4], ul_s[lane * 4 + 1],
                            ul_s[lane * 4 + 2], ul_s[lane * 4 + 3]);
    for (int tt = 0; tt < 64; ++tt) {
      int t = wid * 64 + tt;
      u32 rw0 = ((const u32*)(hs + ((size_t)(t + 1) * B_ + b) * H_))[lane * 2];
      u32 rw1 = ((const u32*)(hs + ((size_t)(t + 1) * B_ + b) * H_))[lane * 2 + 1];
      union { u32 uu; float f; } f0, f1, f2, f3;
      f0.uu = rw0 << 16; f1.uu = rw0 & 0xFFFF0000u;
      f2.uu = rw1 << 16; f3.uu = rw1 & 0xFFFF0000u;
      float p = f0.f * ul.x + f1.f * ul.y + f2.f * ul.z + f3.f * ul.w;
#pragma unroll
      for (int off = 32; off > 0; off >>= 1) p += __shfl_xor(p, off, 64);
      if (lane == 0) sc[t] = (p + db) * scale;
    }
    __syncthreads();
    float v = sc[tid];
    red[tid] = v;
    __syncthreads();
    for (int s2 = 128; s2 > 0; s2 >>= 1) {
      if (tid < s2) red[tid] = fmaxf(red[tid], red[tid + s2]);
      __syncthreads();
    }
    float m = red[0];
    __syncthreads();
    float e = __expf(v - m);
    red[tid] = e;
    __syncthreads();
    for (int s2 = 128; s2 > 0; s2 >>= 1) {
      if (tid < s2) red[tid] += red[tid + s2];
      __syncthreads();
    }
    float inv = 1.f / red[0];
    __syncthreads();
    sc[tid] = e * inv;
    __syncthreads();
    float a0 = 0.f, a1 = 0.f;
#pragma unroll 8
    for (int t = 0; t < 128; ++t) {
      a0 += sc[t]       * b2f(hs[((size_t)(t + 1) * B_ + b) * H_ + tid]);
      a1 += sc[t + 128] * b2f(hs[((size_t)(t + 129) * B_ + b) * H_ + tid]);
    }
    wv_s[tid] = a0 + a1;
    __syncthreads();
  }

  // ---- phase C (k_ao): merged_state = [Wov @ w_b + bov, s_b] ----
  {
    for (int i = tid; i < E_; i += 256) {
      float a0 = bov[i], a1 = 0.f;
#pragma unroll 8
      for (int jj = 0; jj < 128; ++jj) {
        a0 += Wovt[(size_t)jj * E_ + i] * wv_s[jj];
        a1 += Wovt[(size_t)(jj + 128) * E_ + i] * wv_s[jj + 128];
      }
      mst_l[i] = a0 + a1;
    }
    if (tid < F_) mst_l[E_ + tid] = s[(size_t)b * F_ + tid];
    __syncthreads();
  }

  // ---- phase D (k_vqc): 10-qubit statevector sim ----
  {
    if (tid < 40) ang[tid] = tanhf(mst_l[tid]) * PI_F;
    uwl[tid] = uwg[tid];
    if (tid < 64) uwl[256 + tid] = uwg[256 + tid];
#pragma unroll
    for (int k = 0; k < 4; ++k) psi[tid + k * 256] = make_float2(0.03125f, 0.f);
    __syncthreads();
    for (int l = 0; l < 4; ++l) {
      for (int q = 0; q < 10; ++q) {
        int lq = l * 10 + q;
        float a = ang[lq];
        float ca = __cosf(0.5f * a), sa = __sinf(0.5f * a);
        float cs = ca * sa;
        float2 m00 = make_float2(ca * ca, sa * sa);
        float2 m01 = make_float2(-cs, -cs);
        float2 m10 = make_float2(cs, -cs);
        float2 m11 = make_float2(ca * ca, -sa * sa);
        const float* uwp = &uwl[lq * 8];
        float2 a00 = make_float2(uwp[0], uwp[1]), a01 = make_float2(uwp[2], uwp[3]);
        float2 a10 = make_float2(uwp[4], uwp[5]), a11 = make_float2(uwp[6], uwp[7]);
        float2 u00 = cadd(cmul(a00, m00), cmul(a01, m10));
        float2 u01 = cadd(cmul(a00, m01), cmul(a01, m11));
        float2 u10 = cadd(cmul(a10, m00), cmul(a11, m10));
        float2 u11 = cadd(cmul(a10, m01), cmul(a11, m11));
        int bp = 9 - q;
        __syncthreads();
#pragma unroll
        for (int k = 0; k < 2; ++k) {
          int p = tid + k * 256;
          int i0 = ((p >> bp) << (bp + 1)) | (p & ((1 << bp) - 1));
          int i1 = i0 | (1 << bp);
          float2 A0 = psi[i0], A1 = psi[i1];
          psi[i0] = cadd(cmul(u00, A0), cmul(u01, A1));
          psi[i1] = cadd(cmul(u10, A0), cmul(u11, A1));
        }
      }
      for (int q = 0; q < 9; ++q) {  // CNOT(q, q+1): adjacent bits
        int lo = 8 - q;
        __syncthreads();
        int p = tid;
        int i0 = ((p >> lo) << (lo + 2)) | (2 << lo) | (p & ((1 << lo) - 1));
        int i1 = i0 | (1 << lo);
        float2 tmp = psi[i0]; psi[i0] = psi[i1]; psi[i1] = tmp;
      }
      __syncthreads();  // CNOT(9, 0): ctrl bit0, tgt bit9
      {
        int i0 = (tid << 1) | 1;
        int i1 = i0 | 512;
        float2 tmp = psi[i0]; psi[i0] = psi[i1]; psi[i1] = tmp;
      }
    }
    __syncthreads();
    float acc[10];
#pragma unroll
    for (int q = 0; q < 10; ++q) acc[q] = 0.f;
#pragma unroll
    for (int k = 0; k < 4; ++k) {
      int idx = tid + k * 256;
      float2 A = psi[idx];
      float pr = A.x * A.x + A.y * A.y;
#pragma unroll
      for (int q = 0; q < 10; ++q) acc[q] += ((idx >> (9 - q)) & 1) ? -pr : pr;
    }
#pragma unroll
    for (int q = 0; q < 10; ++q) {
      float vq = acc[q];
#pragma unroll
      for (int off = 32; off > 0; off >>= 1) vq += __shfl_xor(vq, off, 64);
      if (lane == 0) part[wid][q] = vq;
    }
    __syncthreads();
    if (tid < 10) qf_s[tid] = part[0][tid] + part[1][tid] + part[2][tid] + part[3][tid];
  }

  // ---- phase E (k_mlp): x1 = relu([mst,qf] @ W1^T + b1); out = x1 @ W2^T + b2
  {
    for (int i = tid; i < DM; i += 256) mg[i] = mst_l[i];
    if (tid < 10) mg[DM + tid] = qf_s[tid];
    __syncthreads();
    float a0 = b1[tid], a1 = b1[tid + 256];
#pragma unroll 8
    for (int k = 0; k < KMLP; ++k) {
      float m = mg[k];
      a0 += W1t[(size_t)k * NL1 + tid] * m;
      a1 += W1t[(size_t)k * NL1 + tid + 256] * m;
    }
    x1[tid] = fmaxf(a0, 0.f);
    x1[tid + 256] = fmaxf(a1, 0.f);
    __syncthreads();
    int a = tid >> 5, l32 = tid & 31;
    float p = 0.f;
    for (int k = l32; k < NL1; k += 32) p += x1[k] * W2[(size_t)a * NL1 + k];
    red[tid] = p;
    __syncthreads();
    if (tid < 8) {
      float acc = b2[tid];
#pragma unroll
      for (int i = 0; i < 32; ++i) acc += red[tid * 32 + i];
      out[(size_t)b * NACT + tid] = acc;
    }
  }
}

// ---------------------------------------------------------------------------
extern "C" void kernel_launch(void* const* d_in, const int* in_sizes, int n_in,
                              void* d_out, int out_size, void* d_ws, size_t ws_size,
                              hipStream_t stream) {
  const float* s      = (const float*)d_in[0];
  const float* lstm_s = (const float*)d_in[1];
  const float* W_ih   = (const float*)d_in[2];
  const float* W_hh   = (const float*)d_in[3];
  const float* b_ih   = (const float*)d_in[4];
  const float* b_hh   = (const float*)d_in[5];
  const float* projW  = (const float*)d_in[6];
  const float* projb  = (const float*)d_in[7];
  const float* ipw    = (const float*)d_in[8];
  const float* ipb    = (const float*)d_in[9];
  const float* opw    = (const float*)d_in[10];
  const float* opb    = (const float*)d_in[11];
  const float* qw     = (const float*)d_in[12];
  const float* W1     = (const float*)d_in[13];
  const float* b1     = (const float*)d_in[14];
  const float* W2     = (const float*)d_in[15];
  const float* b2     = (const float*)d_in[16];
  float* out = (float*)d_out;

  char* wsb = (char*)d_ws;
  size_t off = 0;
  auto alloc = [&](size_t bytes) -> void* {
    void* p = wsb + off;
    off = (off + bytes + 255) & ~(size_t)255;
    return p;
  };
  u16*  xbf  = (u16*)alloc((size_t)T_ * B_ * DIN * 2);
  u16*  hs   = (u16*)alloc((size_t)(T_ + 1) * B_ * H_ * 2);
  u16*  Wg   = (u16*)alloc((size_t)G4 * 384 * 2);
  float* bb  = (float*)alloc(G4 * 4);
  float* bkp = (float*)alloc(E_ * 4);
  float* bvp = (float*)alloc(E_ * 4);
  float* WuT = (float*)alloc((size_t)E_ * H_ * 4);
  float* bu  = (float*)alloc(H_ * 4);
  float* wd  = (float*)alloc(E_ * 4);
  float* ddp = (float*)alloc(256);
  float* Wovt= (float*)alloc((size_t)H_ * E_ * 4);
  float* bov = (float*)alloc(E_ * 4);
  float* uw  = (float*)alloc(40 * 8 * 4);
  float* W1t = (float*)alloc((size_t)KMLP * NL1 * 4);
  u32*  cnt  = (u32*)alloc(1024 * 4);
  (void)ws_size; (void)in_sizes; (void)n_in; (void)out_size;

  hipLaunchKernelGGL(k_prep1, dim3(8453), dim3(256), 0, stream,
                     lstm_s, W_ih, W_hh, b_ih, b_hh, ipw, ipb, projb, qw,
                     xbf, hs, Wg, bb, uw, bkp, bvp, cnt);

  LstmArgs la;
  la.xbf = xbf; la.hs = hs; la.Wg = Wg; la.bb = bb; la.cnt = cnt;
  la.ipw = ipw; la.ipb = ipb; la.projW = projW; la.opw = opw; la.opb = opb;
  la.bkp = bkp; la.bvp = bvp; la.W1 = W1; la.W1t = W1t;
  la.WuT = WuT; la.bu = bu; la.wd = wd; la.ddp = ddp; la.Wovt = Wovt; la.bov = bov;
  void* kargs[] = { (void*)&la };
  hipError_t ce = hipLaunchCooperativeKernel(reinterpret_cast<const void*>(&k_lstm),
                                             dim3(512), dim3(256), kargs, 0, stream);
  if (ce != hipSuccess) {
    // fallback: plain launch (512 blocks at 2/CU co-schedule in practice)
    hipLaunchKernelGGL(k_lstm, dim3(512), dim3(256), 0, stream, la);
  }

  hipLaunchKernelGGL(k_post, dim3(512), dim3(256), 0, stream,
                     hs, s, WuT, bu, wd, ddp, Wovt, bov, uw, W1t, b1, W2, b2, out);
}